// Round 1
// baseline (2059.381 us; speedup 1.0000x reference)
//
#include <hip/hip_runtime.h>
#include <hip/hip_bf16.h>
#include <math.h>

// Problem constants
#define BATCH    2
#define SEQ      2048
#define DMODEL   1024
#define DSSM     2048
#define NHEADS   32
#define DHEAD    64
#define DSTATE   128
#define CONVDIM  2304     // DSSM + 2*DSTATE
#define DINPROJ  4384     // 2*2048 + 2*128 + 32
#define CHUNK    256
#define NCHUNK   8
#define ROWS     (BATCH*SEQ)          // 4096
#define EPSF     1e-5f

// ---------------------------------------------------------------------------
// GEMM: C[M,N] = A[M,K] * B[N,K]^T   (both row-major, K contiguous)
// 64x64 tile, BK=32, 256 threads, 4x4 microtile per thread.
// ---------------------------------------------------------------------------
#define BM 64
#define BN 64
#define BKK 32

__global__ __launch_bounds__(256) void gemm_tn(const float* __restrict__ A,
                                               const float* __restrict__ B,
                                               float* __restrict__ C,
                                               int M, int N, int K) {
    __shared__ float As[BM][BKK + 1];
    __shared__ float Bs[BN][BKK + 1];
    const int tid = threadIdx.x;
    const int bm = blockIdx.y * BM;
    const int bn = blockIdx.x * BN;
    const int lr = tid >> 3;          // 0..31
    const int lk = (tid & 7) * 4;     // 0..28
    const int tx = tid & 15;
    const int ty = tid >> 4;
    float c[4][4] = {};

    for (int k0 = 0; k0 < K; k0 += BKK) {
        float4 a0 = *(const float4*)(A + (size_t)(bm + lr) * K + k0 + lk);
        float4 a1 = *(const float4*)(A + (size_t)(bm + lr + 32) * K + k0 + lk);
        float4 b0 = make_float4(0.f, 0.f, 0.f, 0.f);
        float4 b1 = make_float4(0.f, 0.f, 0.f, 0.f);
        int n0 = bn + lr, n1 = bn + lr + 32;
        if (n0 < N) b0 = *(const float4*)(B + (size_t)n0 * K + k0 + lk);
        if (n1 < N) b1 = *(const float4*)(B + (size_t)n1 * K + k0 + lk);
        As[lr][lk] = a0.x; As[lr][lk+1] = a0.y; As[lr][lk+2] = a0.z; As[lr][lk+3] = a0.w;
        As[lr+32][lk] = a1.x; As[lr+32][lk+1] = a1.y; As[lr+32][lk+2] = a1.z; As[lr+32][lk+3] = a1.w;
        Bs[lr][lk] = b0.x; Bs[lr][lk+1] = b0.y; Bs[lr][lk+2] = b0.z; Bs[lr][lk+3] = b0.w;
        Bs[lr+32][lk] = b1.x; Bs[lr+32][lk+1] = b1.y; Bs[lr+32][lk+2] = b1.z; Bs[lr+32][lk+3] = b1.w;
        __syncthreads();
        #pragma unroll
        for (int kk = 0; kk < BKK; ++kk) {
            float av[4], bv[4];
            #pragma unroll
            for (int i = 0; i < 4; ++i) { av[i] = As[ty*4 + i][kk]; bv[i] = Bs[tx*4 + i][kk]; }
            #pragma unroll
            for (int i = 0; i < 4; ++i)
                #pragma unroll
                for (int j = 0; j < 4; ++j) c[i][j] += av[i] * bv[j];
        }
        __syncthreads();
    }
    #pragma unroll
    for (int i = 0; i < 4; ++i) {
        int row = bm + ty*4 + i;
        #pragma unroll
        for (int j = 0; j < 4; ++j) {
            int col = bn + tx*4 + j;
            if (col < N) C[(size_t)row * N + col] = c[i][j];
        }
    }
}

// ---------------------------------------------------------------------------
// Causal depthwise conv (k=4) + bias + SiLU over the xBC slice of zxbcdt.
// ---------------------------------------------------------------------------
__global__ __launch_bounds__(256) void conv_silu_kernel(const float* __restrict__ zx,
                                                        const float* __restrict__ conv_w,
                                                        const float* __restrict__ conv_b,
                                                        float* __restrict__ xbc) {
    int idx = blockIdx.x * 256 + threadIdx.x;
    if (idx >= ROWS * CONVDIM) return;
    int c = idx % CONVDIM;
    int m = idx / CONVDIM;
    int l = m & (SEQ - 1);
    int b = m >> 11;
    float acc = conv_b[c];
    #pragma unroll
    for (int k = 0; k < 4; ++k) {
        int ls = l - 3 + k;
        if (ls >= 0)
            acc += zx[((size_t)(b * SEQ + ls)) * DINPROJ + DSSM + c] * conv_w[c * 4 + k];
    }
    float s = acc / (1.f + expf(-acc));
    xbc[(size_t)m * CONVDIM + c] = s;
}

// ---------------------------------------------------------------------------
// dt = softplus(dt_raw + dt_bias)
// ---------------------------------------------------------------------------
__global__ __launch_bounds__(256) void dt_kernel(const float* __restrict__ zx,
                                                 const float* __restrict__ dt_bias,
                                                 float* __restrict__ dt) {
    int idx = blockIdx.x * 256 + threadIdx.x;
    if (idx >= ROWS * NHEADS) return;
    int h = idx & 31;
    int m = idx >> 5;
    float v = zx[(size_t)m * DINPROJ + (DSSM + CONVDIM) + h] + dt_bias[h];
    dt[idx] = (v > 20.f) ? v : log1pf(expf(v));
}

// ---------------------------------------------------------------------------
// Per-(b,chunk,head) inclusive cumsum of dA = dt * (-exp(A_log))
// One thread per (b,c,h): 512 threads total.
// ---------------------------------------------------------------------------
__global__ void cumsum_kernel(const float* __restrict__ dt,
                              const float* __restrict__ A_log,
                              float* __restrict__ cum) {
    int t = blockIdx.x * 256 + threadIdx.x;
    if (t >= BATCH * NCHUNK * NHEADS) return;
    int h = t & 31;
    int bc = t >> 5;                 // b*8 + c
    float A = -expf(A_log[h]);
    float acc = 0.f;
    for (int l = 0; l < CHUNK; ++l) {
        size_t idx = ((size_t)bc * CHUNK + l) * NHEADS + h;
        acc += dt[idx] * A;
        cum[idx] = acc;
    }
}

// ---------------------------------------------------------------------------
// Chunk final states: S[b,c,h,p,n] = sum_l B[l,n] * exp(cum_last-cum[l])*dt[l] * x[l,p]
// One block per (b,c,h) = 512 blocks.
// ---------------------------------------------------------------------------
__global__ __launch_bounds__(256) void chunk_state_kernel(const float* __restrict__ xbc,
                                                          const float* __restrict__ dt,
                                                          const float* __restrict__ cum,
                                                          float* __restrict__ S) {
    int bid = blockIdx.x;            // bc*32 + h
    int h = bid & 31, bc = bid >> 5;
    __shared__ float xs[64][64];
    __shared__ float Bsl[64][128];
    __shared__ float coef[64];
    int t = threadIdx.x;
    int n = t & 127, pg = t >> 7;    // pg in {0,1}
    float cum_last = cum[((size_t)bc * CHUNK + 255) * NHEADS + h];
    float acc[32];
    #pragma unroll
    for (int i = 0; i < 32; ++i) acc[i] = 0.f;

    for (int lt = 0; lt < 4; ++lt) {
        for (int i = 0; i < 16; ++i) {
            int e = t + i * 256; int ls = e >> 6, p = e & 63;
            int m = bc * CHUNK + lt * 64 + ls;
            xs[ls][p] = xbc[(size_t)m * CONVDIM + h * 64 + p];
        }
        for (int i = 0; i < 32; ++i) {
            int e = t + i * 256; int ls = e >> 7, nn = e & 127;
            int m = bc * CHUNK + lt * 64 + ls;
            Bsl[ls][nn] = xbc[(size_t)m * CONVDIM + DSSM + nn];
        }
        if (t < 64) {
            int l = lt * 64 + t;
            size_t ci = ((size_t)bc * CHUNK + l) * NHEADS + h;
            coef[t] = expf(cum_last - cum[ci]) * dt[ci];
        }
        __syncthreads();
        #pragma unroll 4
        for (int ls = 0; ls < 64; ++ls) {
            float bv = Bsl[ls][n] * coef[ls];
            #pragma unroll
            for (int p = 0; p < 32; ++p) acc[p] += bv * xs[ls][pg * 32 + p];
        }
        __syncthreads();
    }
    size_t base = (size_t)bid * (DHEAD * DSTATE);
    #pragma unroll
    for (int p = 0; p < 32; ++p)
        S[base + (size_t)(pg * 32 + p) * DSTATE + n] = acc[p];
}

// ---------------------------------------------------------------------------
// Inter-chunk scan (sequential over 8 chunks). Overwrites S[c] with the state
// ENTERING chunk c. One block per (b,h) = 64 blocks.
// ---------------------------------------------------------------------------
__global__ __launch_bounds__(256) void scan_kernel(const float* __restrict__ cum,
                                                   float* __restrict__ S) {
    int bid = blockIdx.x;            // b*32 + h
    int h = bid & 31, b = bid >> 5;
    int t = threadIdx.x;
    float carry[32];
    #pragma unroll
    for (int i = 0; i < 32; ++i) carry[i] = 0.f;
    for (int c = 0; c < NCHUNK; ++c) {
        int bc = b * NCHUNK + c;
        float decay = expf(cum[((size_t)bc * CHUNK + 255) * NHEADS + h]);
        size_t base = ((size_t)(bc * NHEADS + h)) * (DHEAD * DSTATE);
        #pragma unroll
        for (int i = 0; i < 32; ++i) {
            size_t idx = base + t + i * 256;
            float s = S[idx];
            float nw = carry[i] * decay + s;
            S[idx] = carry[i];
            carry[i] = nw;
        }
    }
}

// ---------------------------------------------------------------------------
// Y = intra-chunk (masked C B^T * decay * dt @ x) + inter-chunk (C*exp(cum) @ prev)
//   + D*x.   One block per (b,c,h) = 512 blocks; thread = row l in chunk.
// ---------------------------------------------------------------------------
__global__ __launch_bounds__(256) void y_kernel(const float* __restrict__ xbc,
                                                const float* __restrict__ dt,
                                                const float* __restrict__ cum,
                                                const float* __restrict__ Sprev,
                                                const float* __restrict__ Dp,
                                                float* __restrict__ y) {
    int bid = blockIdx.x;            // bc*32 + h
    int h = bid & 31, bc = bid >> 5;
    __shared__ float prevT[128][65];
    __shared__ float cumL[256];
    __shared__ float dtL[256];
    __shared__ float Bsl[32][128];
    __shared__ float xs[32][64];
    const int l = threadIdx.x;
    const int m = bc * CHUNK + l;

    cumL[l] = cum[((size_t)bc * CHUNK + l) * NHEADS + h];
    dtL[l]  = dt[((size_t)bc * CHUNK + l) * NHEADS + h];
    {
        size_t base = (size_t)bid * (DHEAD * DSTATE);
        for (int i = 0; i < 32; ++i) {
            int e = l + i * 256; int p = e >> 7, n = e & 127;
            prevT[n][p] = Sprev[base + e];
        }
    }
    __syncthreads();

    float acc[64];
    #pragma unroll
    for (int p = 0; p < 64; ++p) acc[p] = 0.f;

    const float* Crow = xbc + (size_t)m * CONVDIM + (DSSM + DSTATE);
    float el = expf(cumL[l]);

    // inter-chunk: acc[p] += exp(cum[l]) * sum_n C[l,n]*prev[p,n]
    for (int n4 = 0; n4 < 32; ++n4) {
        float4 cv = *(const float4*)(Crow + n4 * 4);
        float c0 = cv.x * el, c1 = cv.y * el, c2 = cv.z * el, c3 = cv.w * el;
        #pragma unroll
        for (int p = 0; p < 64; ++p)
            acc[p] += c0 * prevT[n4*4+0][p] + c1 * prevT[n4*4+1][p]
                    + c2 * prevT[n4*4+2][p] + c3 * prevT[n4*4+3][p];
    }

    // intra-chunk, s-tiles of 32
    for (int st = 0; st < 8; ++st) {
        __syncthreads();
        for (int i = 0; i < 16; ++i) {
            int e = l + i * 256; int ss = e >> 7, n = e & 127;
            int mm = bc * CHUNK + st * 32 + ss;
            Bsl[ss][n] = xbc[(size_t)mm * CONVDIM + DSSM + n];
        }
        for (int i = 0; i < 8; ++i) {
            int e = l + i * 256; int ss = e >> 6, p = e & 63;
            int mm = bc * CHUNK + st * 32 + ss;
            xs[ss][p] = xbc[(size_t)mm * CONVDIM + h * 64 + p];
        }
        __syncthreads();
        if (st * 32 <= l) {
            float cb[32];
            #pragma unroll
            for (int ss = 0; ss < 32; ++ss) cb[ss] = 0.f;
            for (int n4 = 0; n4 < 32; ++n4) {
                float4 cv = *(const float4*)(Crow + n4 * 4);
                #pragma unroll
                for (int ss = 0; ss < 32; ++ss)
                    cb[ss] += cv.x * Bsl[ss][n4*4+0] + cv.y * Bsl[ss][n4*4+1]
                            + cv.z * Bsl[ss][n4*4+2] + cv.w * Bsl[ss][n4*4+3];
            }
            #pragma unroll 4
            for (int ss = 0; ss < 32; ++ss) {
                int s = st * 32 + ss;
                if (s <= l) {
                    float coefv = expf(cumL[l] - cumL[s]) * dtL[s];
                    float cbv = cb[ss] * coefv;
                    #pragma unroll
                    for (int p = 0; p < 64; ++p) acc[p] += cbv * xs[ss][p];
                }
            }
        }
    }

    float dv = Dp[h];
    const float* xrow = xbc + (size_t)m * CONVDIM + h * 64;
    float* yrow = y + (size_t)m * DSSM + h * 64;
    #pragma unroll
    for (int p4 = 0; p4 < 16; ++p4) {
        float4 xv = *(const float4*)(xrow + p4 * 4);
        float4 ov;
        ov.x = acc[p4*4+0] + dv * xv.x;
        ov.y = acc[p4*4+1] + dv * xv.y;
        ov.z = acc[p4*4+2] + dv * xv.z;
        ov.w = acc[p4*4+3] + dv * xv.w;
        *(float4*)(yrow + p4 * 4) = ov;
    }
}

// ---------------------------------------------------------------------------
// Gated RMSNorm: yg = y*silu(z); y = yg*rsqrt(mean(yg^2)+eps)*norm_w  (in-place)
// One block per row (4096 blocks).
// ---------------------------------------------------------------------------
__global__ __launch_bounds__(256) void norm_kernel(float* __restrict__ y,
                                                   const float* __restrict__ zx,
                                                   const float* __restrict__ norm_w) {
    int m = blockIdx.x;
    int t = threadIdx.x;
    float* yrow = y + (size_t)m * DSSM;
    const float* zrow = zx + (size_t)m * DINPROJ;   // z slice = cols [0,2048)
    float yg[8];
    float ss = 0.f;
    #pragma unroll
    for (int q = 0; q < 2; ++q) {
        float4 yv = *(const float4*)(yrow + t*8 + q*4);
        float4 zv = *(const float4*)(zrow + t*8 + q*4);
        float zvals[4] = {zv.x, zv.y, zv.z, zv.w};
        float yvals[4] = {yv.x, yv.y, yv.z, yv.w};
        #pragma unroll
        for (int i = 0; i < 4; ++i) {
            float sz = zvals[i] / (1.f + expf(-zvals[i]));
            float g = yvals[i] * sz;
            yg[q*4+i] = g;
            ss += g * g;
        }
    }
    #pragma unroll
    for (int off = 32; off > 0; off >>= 1) ss += __shfl_xor(ss, off, 64);
    __shared__ float red[4];
    if ((t & 63) == 0) red[t >> 6] = ss;
    __syncthreads();
    float tot = red[0] + red[1] + red[2] + red[3];
    float inv = rsqrtf(tot / (float)DSSM + EPSF);
    #pragma unroll
    for (int q = 0; q < 2; ++q) {
        float4 ov;
        ov.x = yg[q*4+0] * inv * norm_w[t*8 + q*4 + 0];
        ov.y = yg[q*4+1] * inv * norm_w[t*8 + q*4 + 1];
        ov.z = yg[q*4+2] * inv * norm_w[t*8 + q*4 + 2];
        ov.w = yg[q*4+3] * inv * norm_w[t*8 + q*4 + 3];
        *(float4*)(yrow + t*8 + q*4) = ov;
    }
}

// ---------------------------------------------------------------------------
extern "C" void kernel_launch(void* const* d_in, const int* in_sizes, int n_in,
                              void* d_out, int out_size, void* d_ws, size_t ws_size,
                              hipStream_t stream) {
    (void)in_sizes; (void)n_in; (void)out_size; (void)ws_size;
    const float* u       = (const float*)d_in[0];
    const float* W_in    = (const float*)d_in[1];
    const float* conv_w  = (const float*)d_in[2];
    const float* conv_b  = (const float*)d_in[3];
    const float* dt_bias = (const float*)d_in[4];
    const float* A_log   = (const float*)d_in[5];
    const float* Dp      = (const float*)d_in[6];
    const float* norm_w  = (const float*)d_in[7];
    const float* W_out   = (const float*)d_in[8];
    float* out = (float*)d_out;

    // workspace layout (floats)
    float* zx   = (float*)d_ws;                       // ROWS*DINPROJ   = 17,956,864
    float* xbc  = zx   + (size_t)ROWS * DINPROJ;      // ROWS*CONVDIM   =  9,437,184
    float* dtb  = xbc  + (size_t)ROWS * CONVDIM;      // ROWS*NHEADS    =    131,072
    float* cum  = dtb  + (size_t)ROWS * NHEADS;       // ROWS*NHEADS    =    131,072
    float* Sbuf = cum  + (size_t)ROWS * NHEADS;       // B*nc*H*P*N     =  4,194,304
    float* yb   = Sbuf + (size_t)BATCH*NCHUNK*NHEADS*DHEAD*DSTATE; // ROWS*DSSM = 8,388,608

    // 1. in_proj: zx = u @ W_in^T
    gemm_tn<<<dim3((DINPROJ + BN - 1) / BN, ROWS / BM), 256, 0, stream>>>(
        u, W_in, zx, ROWS, DINPROJ, DMODEL);
    // 2. conv + silu
    conv_silu_kernel<<<(ROWS * CONVDIM + 255) / 256, 256, 0, stream>>>(zx, conv_w, conv_b, xbc);
    // 3. dt = softplus(dt_raw + bias)
    dt_kernel<<<(ROWS * NHEADS + 255) / 256, 256, 0, stream>>>(zx, dt_bias, dtb);
    // 4. per-chunk cumsum of dA
    cumsum_kernel<<<2, 256, 0, stream>>>(dtb, A_log, cum);
    // 5. chunk final states
    chunk_state_kernel<<<BATCH * NCHUNK * NHEADS, 256, 0, stream>>>(xbc, dtb, cum, Sbuf);
    // 6. inter-chunk scan (S -> prev, in place)
    scan_kernel<<<BATCH * NHEADS, 256, 0, stream>>>(cum, Sbuf);
    // 7. Y = intra + inter + D*x
    y_kernel<<<BATCH * NCHUNK * NHEADS, 256, 0, stream>>>(xbc, dtb, cum, Sbuf, Dp, yb);
    // 8. gated RMSNorm (in place on yb)
    norm_kernel<<<ROWS, 256, 0, stream>>>(yb, zx, norm_w);
    // 9. out_proj: out = yb @ W_out^T
    gemm_tn<<<dim3(DMODEL / BN, ROWS / BM), 256, 0, stream>>>(
        yb, W_out, out, ROWS, DMODEL, DSSM);
}

// Round 2
// 1137.308 us; speedup vs baseline: 1.8108x; 1.8108x over previous
//
#include <hip/hip_runtime.h>
#include <hip/hip_bf16.h>
#include <math.h>
#include <stdint.h>

// Problem constants
#define BATCH    2
#define SEQ      2048
#define DMODEL   1024
#define DSSM     2048
#define NHEADS   32
#define DHEAD    64
#define DSTATE   128
#define CONVDIM  2304     // DSSM + 2*DSTATE
#define DINPROJ  4384     // 2*2048 + 2*128 + 32
#define NPAD     4480     // DINPROJ padded to multiple of 128
#define CHUNK    256
#define NCHUNK   8
#define ROWS     (BATCH*SEQ)          // 4096
#define EPSF     1e-5f

typedef _Float16 half8 __attribute__((ext_vector_type(8)));
typedef float f32x4 __attribute__((ext_vector_type(4)));

// global_load_lds: 16B per lane, LDS dest = wave-uniform base + lane*16
static __device__ __forceinline__ void gload_lds16(const void* g, void* l) {
    __builtin_amdgcn_global_load_lds(
        (const __attribute__((address_space(1))) uint32_t*)g,
        (__attribute__((address_space(3))) uint32_t*)l, 16, 0, 0);
}

// ---------------------------------------------------------------------------
// MFMA GEMM (f16 in, f32 out): C[M,N] = A[M,K] * B[N,K]^T
// BM = 32*WM, BN = 32*WN (2x2 waves, each WMxWN frags of 16x16). BK = 32.
// ---------------------------------------------------------------------------
template<int WM, int WN>
__global__ __launch_bounds__(256) void gemm_f16(const _Float16* __restrict__ A,
                                                const _Float16* __restrict__ B,
                                                float* __restrict__ C,
                                                int K, int ldc, int Nc) {
    constexpr int BM = 32 * WM;
    constexpr int BN = 32 * WN;
    __shared__ _Float16 As[BM * 32];
    __shared__ _Float16 Bs[BN * 32];
    const int t  = threadIdx.x;
    const int wv = t >> 6;
    const int ln = t & 63;
    const int wr = wv >> 1, wc = wv & 1;
    const int tm = blockIdx.y * BM;
    const int bn = blockIdx.x * BN;
    const int kb = ln >> 4;          // which 8-k slice of 32
    const int lr = ln & 15;

    f32x4 acc[WM][WN];
    #pragma unroll
    for (int i = 0; i < WM; ++i)
        #pragma unroll
        for (int j = 0; j < WN; ++j) { f32x4 z = {0.f, 0.f, 0.f, 0.f}; acc[i][j] = z; }

    for (int k0 = 0; k0 < K; k0 += 32) {
        // stage A tile (BM x 32) and B tile (BN x 32), linear LDS
        #pragma unroll
        for (int q = 0; q < BM / 64; ++q) {
            int seg = q * 4 + wv;                  // 16 rows per segment
            int row = seg * 16 + (ln >> 2);
            const _Float16* src = A + (size_t)(tm + row) * K + k0 + (ln & 3) * 8;
            gload_lds16(src, (void*)(As + seg * 512));
        }
        #pragma unroll
        for (int q = 0; q < BN / 64; ++q) {
            int seg = q * 4 + wv;
            int row = seg * 16 + (ln >> 2);
            const _Float16* src = B + (size_t)(bn + row) * K + k0 + (ln & 3) * 8;
            gload_lds16(src, (void*)(Bs + seg * 512));
        }
        __syncthreads();

        half8 af[WM], bf[WN];
        #pragma unroll
        for (int mi = 0; mi < WM; ++mi) {
            int r = wr * (16 * WM) + mi * 16 + lr;
            af[mi] = *(const half8*)(As + r * 32 + kb * 8);
        }
        #pragma unroll
        for (int ni = 0; ni < WN; ++ni) {
            int r = wc * (16 * WN) + ni * 16 + lr;
            bf[ni] = *(const half8*)(Bs + r * 32 + kb * 8);
        }
        #pragma unroll
        for (int mi = 0; mi < WM; ++mi)
            #pragma unroll
            for (int ni = 0; ni < WN; ++ni)
                acc[mi][ni] = __builtin_amdgcn_mfma_f32_16x16x32_f16(af[mi], bf[ni], acc[mi][ni], 0, 0, 0);
        __syncthreads();
    }

    // C/D layout: col = lane&15, row = (lane>>4)*4 + reg   [m89]
    #pragma unroll
    for (int mi = 0; mi < WM; ++mi) {
        #pragma unroll
        for (int ni = 0; ni < WN; ++ni) {
            int col = bn + wc * (16 * WN) + ni * 16 + lr;
            if (col < Nc) {
                int row = tm + wr * (16 * WM) + mi * 16 + (ln >> 4) * 4;
                #pragma unroll
                for (int r = 0; r < 4; ++r)
                    C[(size_t)(row + r) * ldc + col] = acc[mi][ni][r];
            }
        }
    }
}

// ---------------------------------------------------------------------------
// fp32 -> f16 cast, 8 elems/thread
// ---------------------------------------------------------------------------
__global__ __launch_bounds__(256) void cast_f16_kernel(const float* __restrict__ src,
                                                       _Float16* __restrict__ dst, int n8) {
    int i = blockIdx.x * 256 + threadIdx.x;
    if (i >= n8) return;
    float4 a = ((const float4*)src)[2 * i];
    float4 b = ((const float4*)src)[2 * i + 1];
    half8 h;
    h[0] = (_Float16)a.x; h[1] = (_Float16)a.y; h[2] = (_Float16)a.z; h[3] = (_Float16)a.w;
    h[4] = (_Float16)b.x; h[5] = (_Float16)b.y; h[6] = (_Float16)b.z; h[7] = (_Float16)b.w;
    ((half8*)dst)[i] = h;
}

// fp32 [srcRows][cols] -> f16 [dstRows][cols], zero pad rows
__global__ __launch_bounds__(256) void cast_pad_f16_kernel(const float* __restrict__ src,
                                                           _Float16* __restrict__ dst,
                                                           int srcRows, int cols, int n8) {
    int i = blockIdx.x * 256 + threadIdx.x;
    if (i >= n8) return;
    int row = (i * 8) / cols;
    half8 h;
    if (row < srcRows) {
        float4 a = ((const float4*)src)[2 * i];
        float4 b = ((const float4*)src)[2 * i + 1];
        h[0] = (_Float16)a.x; h[1] = (_Float16)a.y; h[2] = (_Float16)a.z; h[3] = (_Float16)a.w;
        h[4] = (_Float16)b.x; h[5] = (_Float16)b.y; h[6] = (_Float16)b.z; h[7] = (_Float16)b.w;
    } else {
        #pragma unroll
        for (int q = 0; q < 8; ++q) h[q] = (_Float16)0.f;
    }
    ((half8*)dst)[i] = h;
}

// ---------------------------------------------------------------------------
// Causal depthwise conv (k=4) + bias + SiLU over the xBC slice of zxbcdt.
// ---------------------------------------------------------------------------
__global__ __launch_bounds__(256) void conv_silu_kernel(const float* __restrict__ zx,
                                                        const float* __restrict__ conv_w,
                                                        const float* __restrict__ conv_b,
                                                        float* __restrict__ xbc) {
    int idx = blockIdx.x * 256 + threadIdx.x;
    if (idx >= ROWS * CONVDIM) return;
    int c = idx % CONVDIM;
    int m = idx / CONVDIM;
    int l = m & (SEQ - 1);
    int b = m >> 11;
    float acc = conv_b[c];
    #pragma unroll
    for (int k = 0; k < 4; ++k) {
        int ls = l - 3 + k;
        if (ls >= 0)
            acc += zx[((size_t)(b * SEQ + ls)) * DINPROJ + DSSM + c] * conv_w[c * 4 + k];
    }
    float s = acc / (1.f + expf(-acc));
    xbc[(size_t)m * CONVDIM + c] = s;
}

// ---------------------------------------------------------------------------
__global__ __launch_bounds__(256) void dt_kernel(const float* __restrict__ zx,
                                                 const float* __restrict__ dt_bias,
                                                 float* __restrict__ dt) {
    int idx = blockIdx.x * 256 + threadIdx.x;
    if (idx >= ROWS * NHEADS) return;
    int h = idx & 31;
    int m = idx >> 5;
    float v = zx[(size_t)m * DINPROJ + (DSSM + CONVDIM) + h] + dt_bias[h];
    dt[idx] = (v > 20.f) ? v : log1pf(expf(v));
}

// ---------------------------------------------------------------------------
__global__ void cumsum_kernel(const float* __restrict__ dt,
                              const float* __restrict__ A_log,
                              float* __restrict__ cum) {
    int t = blockIdx.x * 256 + threadIdx.x;
    if (t >= BATCH * NCHUNK * NHEADS) return;
    int h = t & 31;
    int bc = t >> 5;                 // b*8 + c
    float A = -expf(A_log[h]);
    float acc = 0.f;
    for (int l = 0; l < CHUNK; ++l) {
        size_t idx = ((size_t)bc * CHUNK + l) * NHEADS + h;
        acc += dt[idx] * A;
        cum[idx] = acc;
    }
}

// ---------------------------------------------------------------------------
// Chunk final states: S[b,c,h,p,n] = sum_l B[l,n]*exp(cum_last-cum[l])*dt[l]*x[l,p]
// ---------------------------------------------------------------------------
__global__ __launch_bounds__(256) void chunk_state_kernel(const float* __restrict__ xbc,
                                                          const float* __restrict__ dt,
                                                          const float* __restrict__ cum,
                                                          float* __restrict__ S) {
    int bid = blockIdx.x;            // bc*32 + h
    int h = bid & 31, bc = bid >> 5;
    __shared__ float xs[64][64];
    __shared__ float Bsl[64][128];
    __shared__ float coef[64];
    int t = threadIdx.x;
    int n = t & 127, pg = t >> 7;    // pg in {0,1}
    float cum_last = cum[((size_t)bc * CHUNK + 255) * NHEADS + h];
    float acc[32];
    #pragma unroll
    for (int i = 0; i < 32; ++i) acc[i] = 0.f;

    for (int lt = 0; lt < 4; ++lt) {
        for (int i = 0; i < 16; ++i) {
            int e = t + i * 256; int ls = e >> 6, p = e & 63;
            int m = bc * CHUNK + lt * 64 + ls;
            xs[ls][p] = xbc[(size_t)m * CONVDIM + h * 64 + p];
        }
        for (int i = 0; i < 32; ++i) {
            int e = t + i * 256; int ls = e >> 7, nn = e & 127;
            int m = bc * CHUNK + lt * 64 + ls;
            Bsl[ls][nn] = xbc[(size_t)m * CONVDIM + DSSM + nn];
        }
        if (t < 64) {
            int l = lt * 64 + t;
            size_t ci = ((size_t)bc * CHUNK + l) * NHEADS + h;
            coef[t] = expf(cum_last - cum[ci]) * dt[ci];
        }
        __syncthreads();
        #pragma unroll 4
        for (int ls = 0; ls < 64; ++ls) {
            float bv = Bsl[ls][n] * coef[ls];
            #pragma unroll
            for (int p = 0; p < 32; ++p) acc[p] += bv * xs[ls][pg * 32 + p];
        }
        __syncthreads();
    }
    size_t base = (size_t)bid * (DHEAD * DSTATE);
    #pragma unroll
    for (int p = 0; p < 32; ++p)
        S[base + (size_t)(pg * 32 + p) * DSTATE + n] = acc[p];
}

// ---------------------------------------------------------------------------
// Inter-chunk scan; overwrites S[c] with the state ENTERING chunk c.
// ---------------------------------------------------------------------------
__global__ __launch_bounds__(256) void scan_kernel(const float* __restrict__ cum,
                                                   float* __restrict__ S) {
    int bid = blockIdx.x;            // b*32 + h
    int h = bid & 31, b = bid >> 5;
    int t = threadIdx.x;
    float carry[32];
    #pragma unroll
    for (int i = 0; i < 32; ++i) carry[i] = 0.f;
    for (int c = 0; c < NCHUNK; ++c) {
        int bc = b * NCHUNK + c;
        float decay = expf(cum[((size_t)bc * CHUNK + 255) * NHEADS + h]);
        size_t base = ((size_t)(bc * NHEADS + h)) * (DHEAD * DSTATE);
        #pragma unroll
        for (int i = 0; i < 32; ++i) {
            size_t idx = base + t + i * 256;
            float s = S[idx];
            float nw = carry[i] * decay + s;
            S[idx] = carry[i];
            carry[i] = nw;
        }
    }
}

// ---------------------------------------------------------------------------
// Y = intra-chunk + inter-chunk + D*x
// ---------------------------------------------------------------------------
__global__ __launch_bounds__(256) void y_kernel(const float* __restrict__ xbc,
                                                const float* __restrict__ dt,
                                                const float* __restrict__ cum,
                                                const float* __restrict__ Sprev,
                                                const float* __restrict__ Dp,
                                                float* __restrict__ y) {
    int bid = blockIdx.x;            // bc*32 + h
    int h = bid & 31, bc = bid >> 5;
    __shared__ float prevT[128][65];
    __shared__ float cumL[256];
    __shared__ float dtL[256];
    __shared__ float Bsl[32][128];
    __shared__ float xs[32][64];
    const int l = threadIdx.x;
    const int m = bc * CHUNK + l;

    cumL[l] = cum[((size_t)bc * CHUNK + l) * NHEADS + h];
    dtL[l]  = dt[((size_t)bc * CHUNK + l) * NHEADS + h];
    {
        size_t base = (size_t)bid * (DHEAD * DSTATE);
        for (int i = 0; i < 32; ++i) {
            int e = l + i * 256; int p = e >> 7, n = e & 127;
            prevT[n][p] = Sprev[base + e];
        }
    }
    __syncthreads();

    float acc[64];
    #pragma unroll
    for (int p = 0; p < 64; ++p) acc[p] = 0.f;

    const float* Crow = xbc + (size_t)m * CONVDIM + (DSSM + DSTATE);
    float el = expf(cumL[l]);

    for (int n4 = 0; n4 < 32; ++n4) {
        float4 cv = *(const float4*)(Crow + n4 * 4);
        float c0 = cv.x * el, c1 = cv.y * el, c2 = cv.z * el, c3 = cv.w * el;
        #pragma unroll
        for (int p = 0; p < 64; ++p)
            acc[p] += c0 * prevT[n4*4+0][p] + c1 * prevT[n4*4+1][p]
                    + c2 * prevT[n4*4+2][p] + c3 * prevT[n4*4+3][p];
    }

    for (int st = 0; st < 8; ++st) {
        __syncthreads();
        for (int i = 0; i < 16; ++i) {
            int e = l + i * 256; int ss = e >> 7, n = e & 127;
            int mm = bc * CHUNK + st * 32 + ss;
            Bsl[ss][n] = xbc[(size_t)mm * CONVDIM + DSSM + n];
        }
        for (int i = 0; i < 8; ++i) {
            int e = l + i * 256; int ss = e >> 6, p = e & 63;
            int mm = bc * CHUNK + st * 32 + ss;
            xs[ss][p] = xbc[(size_t)mm * CONVDIM + h * 64 + p];
        }
        __syncthreads();
        if (st * 32 <= l) {
            float cb[32];
            #pragma unroll
            for (int ss = 0; ss < 32; ++ss) cb[ss] = 0.f;
            for (int n4 = 0; n4 < 32; ++n4) {
                float4 cv = *(const float4*)(Crow + n4 * 4);
                #pragma unroll
                for (int ss = 0; ss < 32; ++ss)
                    cb[ss] += cv.x * Bsl[ss][n4*4+0] + cv.y * Bsl[ss][n4*4+1]
                            + cv.z * Bsl[ss][n4*4+2] + cv.w * Bsl[ss][n4*4+3];
            }
            #pragma unroll 4
            for (int ss = 0; ss < 32; ++ss) {
                int s = st * 32 + ss;
                if (s <= l) {
                    float coefv = expf(cumL[l] - cumL[s]) * dtL[s];
                    float cbv = cb[ss] * coefv;
                    #pragma unroll
                    for (int p = 0; p < 64; ++p) acc[p] += cbv * xs[ss][p];
                }
            }
        }
    }

    float dv = Dp[h];
    const float* xrow = xbc + (size_t)m * CONVDIM + h * 64;
    float* yrow = y + (size_t)m * DSSM + h * 64;
    #pragma unroll
    for (int p4 = 0; p4 < 16; ++p4) {
        float4 xv = *(const float4*)(xrow + p4 * 4);
        float4 ov;
        ov.x = acc[p4*4+0] + dv * xv.x;
        ov.y = acc[p4*4+1] + dv * xv.y;
        ov.z = acc[p4*4+2] + dv * xv.z;
        ov.w = acc[p4*4+3] + dv * xv.w;
        *(float4*)(yrow + p4 * 4) = ov;
    }
}

// ---------------------------------------------------------------------------
// Gated RMSNorm -> f16 output for out_proj MFMA
// ---------------------------------------------------------------------------
__global__ __launch_bounds__(256) void norm_kernel(const float* __restrict__ y,
                                                   const float* __restrict__ zx,
                                                   const float* __restrict__ norm_w,
                                                   _Float16* __restrict__ outh) {
    int m = blockIdx.x;
    int t = threadIdx.x;
    const float* yrow = y + (size_t)m * DSSM;
    const float* zrow = zx + (size_t)m * DINPROJ;   // z slice = cols [0,2048)
    float yg[8];
    float ss = 0.f;
    #pragma unroll
    for (int q = 0; q < 2; ++q) {
        float4 yv = *(const float4*)(yrow + t*8 + q*4);
        float4 zv = *(const float4*)(zrow + t*8 + q*4);
        float zvals[4] = {zv.x, zv.y, zv.z, zv.w};
        float yvals[4] = {yv.x, yv.y, yv.z, yv.w};
        #pragma unroll
        for (int i = 0; i < 4; ++i) {
            float sz = zvals[i] / (1.f + expf(-zvals[i]));
            float g = yvals[i] * sz;
            yg[q*4+i] = g;
            ss += g * g;
        }
    }
    #pragma unroll
    for (int off = 32; off > 0; off >>= 1) ss += __shfl_xor(ss, off, 64);
    __shared__ float red[4];
    if ((t & 63) == 0) red[t >> 6] = ss;
    __syncthreads();
    float tot = red[0] + red[1] + red[2] + red[3];
    float inv = rsqrtf(tot / (float)DSSM + EPSF);
    half8 h;
    #pragma unroll
    for (int q = 0; q < 8; ++q)
        h[q] = (_Float16)(yg[q] * inv * norm_w[t*8 + q]);
    *(half8*)(outh + (size_t)m * DSSM + t * 8) = h;
}

// ---------------------------------------------------------------------------
extern "C" void kernel_launch(void* const* d_in, const int* in_sizes, int n_in,
                              void* d_out, int out_size, void* d_ws, size_t ws_size,
                              hipStream_t stream) {
    (void)in_sizes; (void)n_in; (void)out_size; (void)ws_size;
    const float* u       = (const float*)d_in[0];
    const float* W_in    = (const float*)d_in[1];
    const float* conv_w  = (const float*)d_in[2];
    const float* conv_b  = (const float*)d_in[3];
    const float* dt_bias = (const float*)d_in[4];
    const float* A_log   = (const float*)d_in[5];
    const float* Dp      = (const float*)d_in[6];
    const float* norm_w  = (const float*)d_in[7];
    const float* W_out   = (const float*)d_in[8];
    float* out = (float*)d_out;

    // workspace layout
    float* zx   = (float*)d_ws;                       // ROWS*DINPROJ
    float* xbc  = zx   + (size_t)ROWS * DINPROJ;      // ROWS*CONVDIM
    float* dtb  = xbc  + (size_t)ROWS * CONVDIM;      // ROWS*NHEADS
    float* cum  = dtb  + (size_t)ROWS * NHEADS;       // ROWS*NHEADS
    float* Sbuf = cum  + (size_t)ROWS * NHEADS;       // B*nc*H*P*N
    float* yb   = Sbuf + (size_t)BATCH*NCHUNK*NHEADS*DHEAD*DSTATE; // ROWS*DSSM
    _Float16* uh    = (_Float16*)(yb + (size_t)ROWS * DSSM);
    _Float16* Wih   = uh    + (size_t)ROWS * DMODEL;      // NPAD x DMODEL
    _Float16* Wouth = Wih   + (size_t)NPAD * DMODEL;      // DMODEL x DSSM
    _Float16* ybh   = Wouth + (size_t)DMODEL * DSSM;      // ROWS x DSSM

    // casts for MFMA operands
    cast_f16_kernel<<<(ROWS * DMODEL / 8 + 255) / 256, 256, 0, stream>>>(u, uh, ROWS * DMODEL / 8);
    cast_pad_f16_kernel<<<(NPAD * DMODEL / 8 + 255) / 256, 256, 0, stream>>>(
        W_in, Wih, DINPROJ, DMODEL, NPAD * DMODEL / 8);
    cast_f16_kernel<<<(DMODEL * DSSM / 8 + 255) / 256, 256, 0, stream>>>(W_out, Wouth, DMODEL * DSSM / 8);

    // 1. in_proj: zx = u @ W_in^T   (MFMA f16, N padded to 4480)
    gemm_f16<4, 4><<<dim3(NPAD / 128, ROWS / 128), 256, 0, stream>>>(
        uh, Wih, zx, DMODEL, DINPROJ, DINPROJ);
    // 2. conv + silu
    conv_silu_kernel<<<(ROWS * CONVDIM + 255) / 256, 256, 0, stream>>>(zx, conv_w, conv_b, xbc);
    // 3. dt
    dt_kernel<<<(ROWS * NHEADS + 255) / 256, 256, 0, stream>>>(zx, dt_bias, dtb);
    // 4. cumsum of dA
    cumsum_kernel<<<2, 256, 0, stream>>>(dtb, A_log, cum);
    // 5. chunk final states
    chunk_state_kernel<<<BATCH * NCHUNK * NHEADS, 256, 0, stream>>>(xbc, dtb, cum, Sbuf);
    // 6. inter-chunk scan
    scan_kernel<<<BATCH * NHEADS, 256, 0, stream>>>(cum, Sbuf);
    // 7. Y
    y_kernel<<<BATCH * NCHUNK * NHEADS, 256, 0, stream>>>(xbc, dtb, cum, Sbuf, Dp, yb);
    // 8. gated RMSNorm -> f16
    norm_kernel<<<ROWS, 256, 0, stream>>>(yb, zx, norm_w, ybh);
    // 9. out_proj: out = ybh @ W_out^T  (MFMA f16, 128x64 tile -> 512 blocks)
    gemm_f16<4, 2><<<dim3(DMODEL / 64, ROWS / 128), 256, 0, stream>>>(
        ybh, Wouth, out, DSSM, DMODEL, DMODEL);
}

// Round 3
// 417.143 us; speedup vs baseline: 4.9369x; 2.7264x over previous
//
#include <hip/hip_runtime.h>
#include <hip/hip_bf16.h>
#include <math.h>
#include <stdint.h>

// Problem constants
#define BATCH    2
#define SEQ      2048
#define DMODEL   1024
#define DSSM     2048
#define NHEADS   32
#define DHEAD    64
#define DSTATE   128
#define CONVDIM  2304     // DSSM + 2*DSTATE
#define DINPROJ  4384     // 2*2048 + 2*128 + 32
#define NPAD     4480     // DINPROJ padded to multiple of 128
#define CHUNK    256
#define NCHUNK   8
#define ROWS     (BATCH*SEQ)          // 4096
#define NBC      (BATCH*NCHUNK)       // 16
#define EPSF     1e-5f
#define CBASE    (DSSM + DSTATE)      // 2176, C columns in xbc

typedef _Float16 half8 __attribute__((ext_vector_type(8)));
typedef float f32x4 __attribute__((ext_vector_type(4)));

// global_load_lds: 16B per lane, LDS dest = wave-uniform base + lane*16
static __device__ __forceinline__ void gload_lds16(const void* g, void* l) {
    __builtin_amdgcn_global_load_lds(
        (const __attribute__((address_space(1))) uint32_t*)g,
        (__attribute__((address_space(3))) uint32_t*)l, 16, 0, 0);
}

// ---------------------------------------------------------------------------
// MFMA GEMM (f16 in, f32 out): C[M,N] = A[M,K] * B[N,K]^T
// ---------------------------------------------------------------------------
template<int WM, int WN>
__global__ __launch_bounds__(256) void gemm_f16(const _Float16* __restrict__ A,
                                                const _Float16* __restrict__ B,
                                                float* __restrict__ C,
                                                int K, int ldc, int Nc) {
    constexpr int BM = 32 * WM;
    constexpr int BN = 32 * WN;
    __shared__ _Float16 As[BM * 32];
    __shared__ _Float16 Bs[BN * 32];
    const int t  = threadIdx.x;
    const int wv = t >> 6;
    const int ln = t & 63;
    const int wr = wv >> 1, wc = wv & 1;
    const int tm = blockIdx.y * BM;
    const int bn = blockIdx.x * BN;
    const int kb = ln >> 4;
    const int lr = ln & 15;

    f32x4 acc[WM][WN];
    #pragma unroll
    for (int i = 0; i < WM; ++i)
        #pragma unroll
        for (int j = 0; j < WN; ++j) { f32x4 z = {0.f, 0.f, 0.f, 0.f}; acc[i][j] = z; }

    for (int k0 = 0; k0 < K; k0 += 32) {
        #pragma unroll
        for (int q = 0; q < BM / 64; ++q) {
            int seg = q * 4 + wv;
            int row = seg * 16 + (ln >> 2);
            const _Float16* src = A + (size_t)(tm + row) * K + k0 + (ln & 3) * 8;
            gload_lds16(src, (void*)(As + seg * 512));
        }
        #pragma unroll
        for (int q = 0; q < BN / 64; ++q) {
            int seg = q * 4 + wv;
            int row = seg * 16 + (ln >> 2);
            const _Float16* src = B + (size_t)(bn + row) * K + k0 + (ln & 3) * 8;
            gload_lds16(src, (void*)(Bs + seg * 512));
        }
        __syncthreads();

        half8 af[WM], bf[WN];
        #pragma unroll
        for (int mi = 0; mi < WM; ++mi) {
            int r = wr * (16 * WM) + mi * 16 + lr;
            af[mi] = *(const half8*)(As + r * 32 + kb * 8);
        }
        #pragma unroll
        for (int ni = 0; ni < WN; ++ni) {
            int r = wc * (16 * WN) + ni * 16 + lr;
            bf[ni] = *(const half8*)(Bs + r * 32 + kb * 8);
        }
        #pragma unroll
        for (int mi = 0; mi < WM; ++mi)
            #pragma unroll
            for (int ni = 0; ni < WN; ++ni)
                acc[mi][ni] = __builtin_amdgcn_mfma_f32_16x16x32_f16(af[mi], bf[ni], acc[mi][ni], 0, 0, 0);
        __syncthreads();
    }

    #pragma unroll
    for (int mi = 0; mi < WM; ++mi) {
        #pragma unroll
        for (int ni = 0; ni < WN; ++ni) {
            int col = bn + wc * (16 * WN) + ni * 16 + lr;
            if (col < Nc) {
                int row = tm + wr * (16 * WM) + mi * 16 + (ln >> 4) * 4;
                #pragma unroll
                for (int r = 0; r < 4; ++r)
                    C[(size_t)(row + r) * ldc + col] = acc[mi][ni][r];
            }
        }
    }
}

// ---------------------------------------------------------------------------
// casts
// ---------------------------------------------------------------------------
__global__ __launch_bounds__(256) void cast_f16_kernel(const float* __restrict__ src,
                                                       _Float16* __restrict__ dst, int n8) {
    int i = blockIdx.x * 256 + threadIdx.x;
    if (i >= n8) return;
    float4 a = ((const float4*)src)[2 * i];
    float4 b = ((const float4*)src)[2 * i + 1];
    half8 h;
    h[0] = (_Float16)a.x; h[1] = (_Float16)a.y; h[2] = (_Float16)a.z; h[3] = (_Float16)a.w;
    h[4] = (_Float16)b.x; h[5] = (_Float16)b.y; h[6] = (_Float16)b.z; h[7] = (_Float16)b.w;
    ((half8*)dst)[i] = h;
}

__global__ __launch_bounds__(256) void cast_pad_f16_kernel(const float* __restrict__ src,
                                                           _Float16* __restrict__ dst,
                                                           int srcRows, int cols, int n8) {
    int i = blockIdx.x * 256 + threadIdx.x;
    if (i >= n8) return;
    int row = (i * 8) / cols;
    half8 h;
    if (row < srcRows) {
        float4 a = ((const float4*)src)[2 * i];
        float4 b = ((const float4*)src)[2 * i + 1];
        h[0] = (_Float16)a.x; h[1] = (_Float16)a.y; h[2] = (_Float16)a.z; h[3] = (_Float16)a.w;
        h[4] = (_Float16)b.x; h[5] = (_Float16)b.y; h[6] = (_Float16)b.z; h[7] = (_Float16)b.w;
    } else {
        #pragma unroll
        for (int q = 0; q < 8; ++q) h[q] = (_Float16)0.f;
    }
    ((half8*)dst)[i] = h;
}

// ---------------------------------------------------------------------------
// Conv + SiLU -> f16 xbc, plus transposed f16 copies xT_g [bc][h][p][s] and
// BT_g [bc][n][s] for the MFMA SSD kernels.
// ---------------------------------------------------------------------------
__global__ __launch_bounds__(256) void conv_silu_kernel(const float* __restrict__ zx,
                                                        const float* __restrict__ conv_w,
                                                        const float* __restrict__ conv_b,
                                                        _Float16* __restrict__ xbc,
                                                        _Float16* __restrict__ xTg,
                                                        _Float16* __restrict__ BTg) {
    int idx = blockIdx.x * 256 + threadIdx.x;
    if (idx >= ROWS * CONVDIM) return;
    int c = idx % CONVDIM;
    int m = idx / CONVDIM;
    int l = m & (SEQ - 1);
    int b = m >> 11;
    float acc = conv_b[c];
    #pragma unroll
    for (int k = 0; k < 4; ++k) {
        int ls = l - 3 + k;
        if (ls >= 0)
            acc += zx[((size_t)(b * SEQ + ls)) * DINPROJ + DSSM + c] * conv_w[c * 4 + k];
    }
    float s = acc / (1.f + expf(-acc));
    _Float16 hv = (_Float16)s;
    xbc[(size_t)m * CONVDIM + c] = hv;
    int bcc = m >> 8;            // b*8 + chunk
    int si  = m & 255;           // pos within chunk
    if (c < DSSM) {
        int hh = c >> 6, p = c & 63;
        xTg[((size_t)(bcc * 32 + hh) * 64 + p) * 256 + si] = hv;
    } else if (c < DSSM + DSTATE) {
        int n = c - DSSM;
        BTg[((size_t)bcc * 128 + n) * 256 + si] = hv;
    }
}

// ---------------------------------------------------------------------------
__global__ __launch_bounds__(256) void dt_kernel(const float* __restrict__ zx,
                                                 const float* __restrict__ dt_bias,
                                                 float* __restrict__ dt) {
    int idx = blockIdx.x * 256 + threadIdx.x;
    if (idx >= ROWS * NHEADS) return;
    int h = idx & 31;
    int m = idx >> 5;
    float v = zx[(size_t)m * DINPROJ + (DSSM + CONVDIM) + h] + dt_bias[h];
    dt[idx] = (v > 20.f) ? v : log1pf(expf(v));
}

__global__ void cumsum_kernel(const float* __restrict__ dt,
                              const float* __restrict__ A_log,
                              float* __restrict__ cum) {
    int t = blockIdx.x * 256 + threadIdx.x;
    if (t >= NBC * NHEADS) return;
    int h = t & 31;
    int bc = t >> 5;
    float A = -expf(A_log[h]);
    float acc = 0.f;
    for (int l = 0; l < CHUNK; ++l) {
        size_t idx = ((size_t)bc * CHUNK + l) * NHEADS + h;
        acc += dt[idx] * A;
        cum[idx] = acc;
    }
}

// ---------------------------------------------------------------------------
// Chunk states via MFMA: S[p][n] = sum_l (coef[l]*x[l,p]) * B[l,n]
// A = coefx[p][l] (from xT_g), B-op = BT[n][l] (from BT_g), k = l.
// Block per (b,c,h); wave w owns n-range [w*32, w*32+32).
// ---------------------------------------------------------------------------
__global__ __launch_bounds__(256) void chunk_state_mfma(const _Float16* __restrict__ xTg,
                                                        const _Float16* __restrict__ BTg,
                                                        const float* __restrict__ dt,
                                                        const float* __restrict__ cum,
                                                        float* __restrict__ S) {
    int bid = blockIdx.x;
    int h = bid & 31, bc = bid >> 5;
    __shared__ _Float16 cxs[64 * 64];      // [p][l-tile], swizzled
    __shared__ _Float16 bts[128 * 64];     // [n][l-tile], swizzled
    __shared__ float coefL[256];
    const int t = threadIdx.x, w = t >> 6, ln = t & 63;
    const int lr = ln & 15, lg = ln >> 4;

    {
        float cl = cum[((size_t)bc * 256 + 255) * 32 + h];
        size_t ci = ((size_t)bc * 256 + t) * 32 + h;
        coefL[t] = expf(cl - cum[ci]) * dt[ci];
    }

    f32x4 sacc[4][2];
    #pragma unroll
    for (int pi = 0; pi < 4; ++pi)
        #pragma unroll
        for (int ni = 0; ni < 2; ++ni) { f32x4 z = {0.f,0.f,0.f,0.f}; sacc[pi][ni] = z; }

    for (int kt = 0; kt < 4; ++kt) {
        __syncthreads();
        // stage coefx tile [64p][64l] with coef applied, swizzled write
        {
            int p = t >> 2, l0 = (t & 3) * 16;
            const _Float16* src = xTg + ((size_t)bid * 64 + p) * 256 + kt * 64;
            #pragma unroll
            for (int q = 0; q < 2; ++q) {
                int c = l0 + q * 8;
                half8 hv = *(const half8*)(src + c);
                half8 ov;
                #pragma unroll
                for (int j = 0; j < 8; ++j)
                    ov[j] = (_Float16)((float)hv[j] * coefL[kt * 64 + c + j]);
                *(half8*)(cxs + p * 64 + (c ^ ((p & 7) << 3))) = ov;
            }
        }
        // stage BT tile [128n][64l] via gload_lds with pre-swizzled source col
        #pragma unroll
        for (int q = 0; q < 4; ++q) {
            int seg = w * 4 + q;
            int r = seg * 8 + (ln >> 3);
            int csw = 8 * ((ln & 7) ^ (r & 7));
            const _Float16* src = BTg + ((size_t)bc * 128 + r) * 256 + kt * 64 + csw;
            gload_lds16(src, (void*)(bts + seg * 512));
        }
        __syncthreads();
        #pragma unroll
        for (int kk = 0; kk < 2; ++kk) {
            int c0 = kk * 32 + lg * 8;
            half8 ax[4], bx[2];
            #pragma unroll
            for (int pi = 0; pi < 4; ++pi) {
                int r = pi * 16 + lr;
                ax[pi] = *(const half8*)(cxs + r * 64 + (c0 ^ ((r & 7) << 3)));
            }
            #pragma unroll
            for (int ni = 0; ni < 2; ++ni) {
                int r = w * 32 + ni * 16 + lr;
                bx[ni] = *(const half8*)(bts + r * 64 + (c0 ^ ((r & 7) << 3)));
            }
            #pragma unroll
            for (int pi = 0; pi < 4; ++pi)
                #pragma unroll
                for (int ni = 0; ni < 2; ++ni)
                    sacc[pi][ni] = __builtin_amdgcn_mfma_f32_16x16x32_f16(ax[pi], bx[ni], sacc[pi][ni], 0, 0, 0);
        }
    }
    float* sb = S + (size_t)bid * (DHEAD * DSTATE);
    #pragma unroll
    for (int pi = 0; pi < 4; ++pi)
        #pragma unroll
        for (int ni = 0; ni < 2; ++ni)
            #pragma unroll
            for (int r = 0; r < 4; ++r) {
                int p = pi * 16 + lg * 4 + r;
                int n = w * 32 + ni * 16 + lr;
                sb[p * 128 + n] = sacc[pi][ni][r];
            }
}

// ---------------------------------------------------------------------------
// Inter-chunk scan; S[c] <- state ENTERING chunk c. Layout-agnostic (flat 8192).
// ---------------------------------------------------------------------------
__global__ __launch_bounds__(256) void scan_kernel(const float* __restrict__ cum,
                                                   float* __restrict__ S) {
    int bid = blockIdx.x;            // b*32 + h
    int h = bid & 31, b = bid >> 5;
    int t = threadIdx.x;
    float carry[32];
    #pragma unroll
    for (int i = 0; i < 32; ++i) carry[i] = 0.f;
    for (int c = 0; c < NCHUNK; ++c) {
        int bc = b * NCHUNK + c;
        float decay = expf(cum[((size_t)bc * CHUNK + 255) * NHEADS + h]);
        size_t base = ((size_t)(bc * NHEADS + h)) * (DHEAD * DSTATE);
        #pragma unroll
        for (int i = 0; i < 32; ++i) {
            size_t idx = base + t + i * 256;
            float s = S[idx];
            float nw = carry[i] * decay + s;
            S[idx] = carry[i];
            carry[i] = nw;
        }
    }
}

// ---------------------------------------------------------------------------
// Y via MFMA: inter = mfma(C, prev); intra = mfma(C,B) -> P(exp,dt,mask) -> LDS
// -> mfma(P, xT). Block per (b,c,h), wave w owns l-tile [w*64, w*64+64).
// ---------------------------------------------------------------------------
__global__ __launch_bounds__(256) void y_mfma(const _Float16* __restrict__ xbc,
                                              const _Float16* __restrict__ xTg,
                                              const float* __restrict__ dt,
                                              const float* __restrict__ cum,
                                              const float* __restrict__ Sprev,
                                              const float* __restrict__ Dp,
                                              float* __restrict__ y) {
    int bid = blockIdx.x;
    int h = bid & 31, bc = bid >> 5;
    __shared__ _Float16 prevh[64 * 128];   // [p][n], swizzled
    __shared__ _Float16 Bs[64 * 128];      // [s][n], swizzled
    __shared__ _Float16 xTs[64 * 64];      // [p][s-tile], swizzled
    __shared__ _Float16 Pw[4 * 64 * 64];   // per-wave P [l][s], swizzled
    __shared__ float cumL[256], dtL[256];
    const int t = threadIdx.x, w = t >> 6, ln = t & 63;
    const int lr = ln & 15, lg = ln >> 4;

    {
        size_t ci = ((size_t)bc * 256 + t) * 32 + h;
        cumL[t] = cum[ci];
        dtL[t]  = dt[ci];
    }
    // stage prev (f32 -> f16, swizzled)
    {
        const float* sp = Sprev + (size_t)bid * (DHEAD * DSTATE);
        int r = t >> 2, c0 = (t & 3) * 32;
        #pragma unroll
        for (int q = 0; q < 4; ++q) {
            int c = c0 + q * 8;
            float4 f0 = *(const float4*)(sp + r * 128 + c);
            float4 f1 = *(const float4*)(sp + r * 128 + c + 4);
            half8 hv;
            hv[0]=(_Float16)f0.x; hv[1]=(_Float16)f0.y; hv[2]=(_Float16)f0.z; hv[3]=(_Float16)f0.w;
            hv[4]=(_Float16)f1.x; hv[5]=(_Float16)f1.y; hv[6]=(_Float16)f1.z; hv[7]=(_Float16)f1.w;
            *(half8*)(prevh + r * 128 + (c ^ ((r & 7) << 3))) = hv;
        }
    }
    // C a-fragments from global (rows l, k = n)
    half8 ca[4][4];
    {
        const _Float16* cb = xbc + ((size_t)(bc * 256 + w * 64)) * CONVDIM + CBASE;
        #pragma unroll
        for (int mi = 0; mi < 4; ++mi)
            #pragma unroll
            for (int kk = 0; kk < 4; ++kk)
                ca[mi][kk] = *(const half8*)(cb + (size_t)(mi * 16 + lr) * CONVDIM + kk * 32 + lg * 8);
    }
    __syncthreads();

    f32x4 yacc[4][4];
    #pragma unroll
    for (int i = 0; i < 4; ++i)
        #pragma unroll
        for (int j = 0; j < 4; ++j) { f32x4 z = {0.f,0.f,0.f,0.f}; yacc[i][j] = z; }

    // inter-chunk: D[l][p] = sum_n C[l,n]*prev[p,n]
    #pragma unroll
    for (int kk = 0; kk < 4; ++kk) {
        int c0 = kk * 32 + lg * 8;
        #pragma unroll
        for (int pi = 0; pi < 4; ++pi) {
            int r = pi * 16 + lr;
            half8 pb = *(const half8*)(prevh + r * 128 + (c0 ^ ((r & 7) << 3)));
            #pragma unroll
            for (int mi = 0; mi < 4; ++mi)
                yacc[mi][pi] = __builtin_amdgcn_mfma_f32_16x16x32_f16(ca[mi][kk], pb, yacc[mi][pi], 0, 0, 0);
        }
    }
    // scale by exp(cum[l])
    #pragma unroll
    for (int mi = 0; mi < 4; ++mi)
        #pragma unroll
        for (int r = 0; r < 4; ++r) {
            float el = expf(cumL[w * 64 + mi * 16 + lg * 4 + r]);
            #pragma unroll
            for (int pi = 0; pi < 4; ++pi) yacc[mi][pi][r] *= el;
        }

    // s-tiles
    for (int st = 0; st < 4; ++st) {
        __syncthreads();
        // stage Bs [64s][128n] via gload_lds, pre-swizzled source col
        #pragma unroll
        for (int q = 0; q < 4; ++q) {
            int seg = w * 4 + q;
            int r = seg * 4 + lg;
            int csw = 8 * (lr ^ (r & 7));
            const _Float16* src = xbc + ((size_t)(bc * 256 + st * 64 + r)) * CONVDIM + DSSM + csw;
            gload_lds16(src, (void*)(Bs + seg * 512));
        }
        // stage xTs [64p][64s] via gload_lds, pre-swizzled
        #pragma unroll
        for (int q = 0; q < 2; ++q) {
            int seg = w * 2 + q;
            int r = seg * 8 + (ln >> 3);
            int csw = 8 * ((ln & 7) ^ (r & 7));
            const _Float16* src = xTg + ((size_t)bid * 64 + r) * 256 + st * 64 + csw;
            gload_lds16(src, (void*)(xTs + seg * 512));
        }
        __syncthreads();
        if (st <= w) {
            f32x4 pacc[4][4];
            #pragma unroll
            for (int i = 0; i < 4; ++i)
                #pragma unroll
                for (int j = 0; j < 4; ++j) { f32x4 z = {0.f,0.f,0.f,0.f}; pacc[i][j] = z; }
            #pragma unroll
            for (int kk = 0; kk < 4; ++kk) {
                int c0 = kk * 32 + lg * 8;
                #pragma unroll
                for (int si = 0; si < 4; ++si) {
                    int r = si * 16 + lr;
                    half8 bb = *(const half8*)(Bs + r * 128 + (c0 ^ ((r & 7) << 3)));
                    #pragma unroll
                    for (int mi = 0; mi < 4; ++mi)
                        pacc[mi][si] = __builtin_amdgcn_mfma_f32_16x16x32_f16(ca[mi][kk], bb, pacc[mi][si], 0, 0, 0);
                }
            }
            // coef + mask + write P (f16) to this wave's LDS buffer
            _Float16* pwb = Pw + w * 4096;
            bool diag = (st == w);
            #pragma unroll
            for (int mi = 0; mi < 4; ++mi) {
                #pragma unroll
                for (int r = 0; r < 4; ++r) {
                    int lloc = mi * 16 + lg * 4 + r;
                    float cl = cumL[w * 64 + lloc];
                    #pragma unroll
                    for (int si = 0; si < 4; ++si) {
                        int scol = si * 16 + lr;
                        int s = st * 64 + scol;
                        float v = 0.f;
                        if (!diag || s <= (w * 64 + lloc))
                            v = pacc[mi][si][r] * expf(cl - cumL[s]) * dtL[s];
                        pwb[lloc * 64 + (scol ^ ((lloc & 7) << 3))] = (_Float16)v;
                    }
                }
            }
            // PV: D[l][p] += sum_s P[l,s] * xT[p,s]
            #pragma unroll
            for (int kk2 = 0; kk2 < 2; ++kk2) {
                int c0 = kk2 * 32 + lg * 8;
                half8 pa[4];
                #pragma unroll
                for (int mi = 0; mi < 4; ++mi) {
                    int r = mi * 16 + lr;
                    pa[mi] = *(const half8*)(pwb + r * 64 + (c0 ^ ((r & 7) << 3)));
                }
                #pragma unroll
                for (int pi = 0; pi < 4; ++pi) {
                    int r = pi * 16 + lr;
                    half8 xb = *(const half8*)(xTs + r * 64 + (c0 ^ ((r & 7) << 3)));
                    #pragma unroll
                    for (int mi = 0; mi < 4; ++mi)
                        yacc[mi][pi] = __builtin_amdgcn_mfma_f32_16x16x32_f16(pa[mi], xb, yacc[mi][pi], 0, 0, 0);
                }
            }
        }
    }

    // epilogue: + D*x, write f32 y
    float dv = Dp[h];
    #pragma unroll
    for (int mi = 0; mi < 4; ++mi) {
        #pragma unroll
        for (int r = 0; r < 4; ++r) {
            int l = w * 64 + mi * 16 + lg * 4 + r;
            size_t row = (size_t)bc * 256 + l;
            #pragma unroll
            for (int pi = 0; pi < 4; ++pi) {
                int p = pi * 16 + lr;
                float xv = (float)xbc[row * CONVDIM + h * 64 + p];
                y[row * DSSM + h * 64 + p] = yacc[mi][pi][r] + dv * xv;
            }
        }
    }
}

// ---------------------------------------------------------------------------
// Gated RMSNorm -> f16 output for out_proj MFMA
// ---------------------------------------------------------------------------
__global__ __launch_bounds__(256) void norm_kernel(const float* __restrict__ y,
                                                   const float* __restrict__ zx,
                                                   const float* __restrict__ norm_w,
                                                   _Float16* __restrict__ outh) {
    int m = blockIdx.x;
    int t = threadIdx.x;
    const float* yrow = y + (size_t)m * DSSM;
    const float* zrow = zx + (size_t)m * DINPROJ;
    float yg[8];
    float ss = 0.f;
    #pragma unroll
    for (int q = 0; q < 2; ++q) {
        float4 yv = *(const float4*)(yrow + t*8 + q*4);
        float4 zv = *(const float4*)(zrow + t*8 + q*4);
        float zvals[4] = {zv.x, zv.y, zv.z, zv.w};
        float yvals[4] = {yv.x, yv.y, yv.z, yv.w};
        #pragma unroll
        for (int i = 0; i < 4; ++i) {
            float sz = zvals[i] / (1.f + expf(-zvals[i]));
            float g = yvals[i] * sz;
            yg[q*4+i] = g;
            ss += g * g;
        }
    }
    #pragma unroll
    for (int off = 32; off > 0; off >>= 1) ss += __shfl_xor(ss, off, 64);
    __shared__ float red[4];
    if ((t & 63) == 0) red[t >> 6] = ss;
    __syncthreads();
    float tot = red[0] + red[1] + red[2] + red[3];
    float inv = rsqrtf(tot / (float)DSSM + EPSF);
    half8 h;
    #pragma unroll
    for (int q = 0; q < 8; ++q)
        h[q] = (_Float16)(yg[q] * inv * norm_w[t*8 + q]);
    *(half8*)(outh + (size_t)m * DSSM + t * 8) = h;
}

// ---------------------------------------------------------------------------
extern "C" void kernel_launch(void* const* d_in, const int* in_sizes, int n_in,
                              void* d_out, int out_size, void* d_ws, size_t ws_size,
                              hipStream_t stream) {
    (void)in_sizes; (void)n_in; (void)out_size; (void)ws_size;
    const float* u       = (const float*)d_in[0];
    const float* W_in    = (const float*)d_in[1];
    const float* conv_w  = (const float*)d_in[2];
    const float* conv_b  = (const float*)d_in[3];
    const float* dt_bias = (const float*)d_in[4];
    const float* A_log   = (const float*)d_in[5];
    const float* Dp      = (const float*)d_in[6];
    const float* norm_w  = (const float*)d_in[7];
    const float* W_out   = (const float*)d_in[8];
    float* out = (float*)d_out;

    // workspace layout
    float* zx   = (float*)d_ws;                       // ROWS*DINPROJ
    float* dtb  = zx   + (size_t)ROWS * DINPROJ;      // ROWS*NHEADS
    float* cum  = dtb  + (size_t)ROWS * NHEADS;
    float* Sbuf = cum  + (size_t)ROWS * NHEADS;       // 512*64*128
    float* yb   = Sbuf + (size_t)NBC * NHEADS * DHEAD * DSTATE;  // ROWS*DSSM
    _Float16* xbc_h = (_Float16*)(yb + (size_t)ROWS * DSSM);     // ROWS*CONVDIM
    _Float16* xTg   = xbc_h + (size_t)ROWS * CONVDIM;            // 512*64*256
    _Float16* BTg   = xTg   + (size_t)NBC * NHEADS * 64 * 256;   // 16*128*256
    _Float16* uh    = BTg   + (size_t)NBC * 128 * 256;
    _Float16* Wih   = uh    + (size_t)ROWS * DMODEL;
    _Float16* Wouth = Wih   + (size_t)NPAD * DMODEL;
    _Float16* ybh   = Wouth + (size_t)DMODEL * DSSM;

    // casts
    cast_f16_kernel<<<(ROWS * DMODEL / 8 + 255) / 256, 256, 0, stream>>>(u, uh, ROWS * DMODEL / 8);
    cast_pad_f16_kernel<<<(NPAD * DMODEL / 8 + 255) / 256, 256, 0, stream>>>(
        W_in, Wih, DINPROJ, DMODEL, NPAD * DMODEL / 8);
    cast_f16_kernel<<<(DMODEL * DSSM / 8 + 255) / 256, 256, 0, stream>>>(W_out, Wouth, DMODEL * DSSM / 8);

    // 1. in_proj
    gemm_f16<4, 4><<<dim3(NPAD / 128, ROWS / 128), 256, 0, stream>>>(
        uh, Wih, zx, DMODEL, DINPROJ, DINPROJ);
    // 2. conv + silu -> f16 xbc + transposed copies
    conv_silu_kernel<<<(ROWS * CONVDIM + 255) / 256, 256, 0, stream>>>(
        zx, conv_w, conv_b, xbc_h, xTg, BTg);
    // 3. dt
    dt_kernel<<<(ROWS * NHEADS + 255) / 256, 256, 0, stream>>>(zx, dt_bias, dtb);
    // 4. cumsum
    cumsum_kernel<<<2, 256, 0, stream>>>(dtb, A_log, cum);
    // 5. chunk states (MFMA)
    chunk_state_mfma<<<NBC * NHEADS, 256, 0, stream>>>(xTg, BTg, dtb, cum, Sbuf);
    // 6. inter-chunk scan
    scan_kernel<<<BATCH * NHEADS, 256, 0, stream>>>(cum, Sbuf);
    // 7. Y (MFMA)
    y_mfma<<<NBC * NHEADS, 256, 0, stream>>>(xbc_h, xTg, dtb, cum, Sbuf, Dp, yb);
    // 8. gated RMSNorm -> f16
    norm_kernel<<<ROWS, 256, 0, stream>>>(yb, zx, norm_w, ybh);
    // 9. out_proj
    gemm_f16<4, 2><<<dim3(DMODEL / 64, ROWS / 128), 256, 0, stream>>>(
        ybh, Wouth, out, DSSM, DMODEL, DMODEL);
}

// Round 4
// 371.521 us; speedup vs baseline: 5.5431x; 1.1228x over previous
//
#include <hip/hip_runtime.h>
#include <hip/hip_bf16.h>
#include <math.h>
#include <stdint.h>

// Problem constants
#define BATCH    2
#define SEQ      2048
#define DMODEL   1024
#define DSSM     2048
#define NHEADS   32
#define DHEAD    64
#define DSTATE   128
#define CONVDIM  2304     // DSSM + 2*DSTATE
#define DINPROJ  4384     // 2*2048 + 2*128 + 32
#define NPAD     4480     // DINPROJ padded to multiple of 128
#define CHUNK    256
#define NCHUNK   8
#define ROWS     (BATCH*SEQ)          // 4096
#define NBC      (BATCH*NCHUNK)       // 16
#define EPSF     1e-5f
#define CBASE    (DSSM + DSTATE)      // 2176, C columns in xbc

typedef _Float16 half8 __attribute__((ext_vector_type(8)));
typedef float f32x4 __attribute__((ext_vector_type(4)));

// global_load_lds: 16B per lane, LDS dest = wave-uniform base + lane*16
static __device__ __forceinline__ void gload_lds16(const void* g, void* l) {
    __builtin_amdgcn_global_load_lds(
        (const __attribute__((address_space(1))) uint32_t*)g,
        (__attribute__((address_space(3))) uint32_t*)l, 16, 0, 0);
}

// ---------------------------------------------------------------------------
// MFMA GEMM (f16 in, f32 out): C[M,N] = A[M,K] * B[N,K]^T
// ---------------------------------------------------------------------------
template<int WM, int WN>
__global__ __launch_bounds__(256) void gemm_f16(const _Float16* __restrict__ A,
                                                const _Float16* __restrict__ B,
                                                float* __restrict__ C,
                                                int K, int ldc, int Nc) {
    constexpr int BM = 32 * WM;
    constexpr int BN = 32 * WN;
    __shared__ _Float16 As[BM * 32];
    __shared__ _Float16 Bs[BN * 32];
    const int t  = threadIdx.x;
    const int wv = t >> 6;
    const int ln = t & 63;
    const int wr = wv >> 1, wc = wv & 1;
    const int tm = blockIdx.y * BM;
    const int bn = blockIdx.x * BN;
    const int kb = ln >> 4;
    const int lr = ln & 15;

    f32x4 acc[WM][WN];
    #pragma unroll
    for (int i = 0; i < WM; ++i)
        #pragma unroll
        for (int j = 0; j < WN; ++j) { f32x4 z = {0.f, 0.f, 0.f, 0.f}; acc[i][j] = z; }

    for (int k0 = 0; k0 < K; k0 += 32) {
        #pragma unroll
        for (int q = 0; q < BM / 64; ++q) {
            int seg = q * 4 + wv;
            int row = seg * 16 + (ln >> 2);
            const _Float16* src = A + (size_t)(tm + row) * K + k0 + (ln & 3) * 8;
            gload_lds16(src, (void*)(As + seg * 512));
        }
        #pragma unroll
        for (int q = 0; q < BN / 64; ++q) {
            int seg = q * 4 + wv;
            int row = seg * 16 + (ln >> 2);
            const _Float16* src = B + (size_t)(bn + row) * K + k0 + (ln & 3) * 8;
            gload_lds16(src, (void*)(Bs + seg * 512));
        }
        __syncthreads();

        half8 af[WM], bf[WN];
        #pragma unroll
        for (int mi = 0; mi < WM; ++mi) {
            int r = wr * (16 * WM) + mi * 16 + lr;
            af[mi] = *(const half8*)(As + r * 32 + kb * 8);
        }
        #pragma unroll
        for (int ni = 0; ni < WN; ++ni) {
            int r = wc * (16 * WN) + ni * 16 + lr;
            bf[ni] = *(const half8*)(Bs + r * 32 + kb * 8);
        }
        #pragma unroll
        for (int mi = 0; mi < WM; ++mi)
            #pragma unroll
            for (int ni = 0; ni < WN; ++ni)
                acc[mi][ni] = __builtin_amdgcn_mfma_f32_16x16x32_f16(af[mi], bf[ni], acc[mi][ni], 0, 0, 0);
        __syncthreads();
    }

    #pragma unroll
    for (int mi = 0; mi < WM; ++mi) {
        #pragma unroll
        for (int ni = 0; ni < WN; ++ni) {
            int col = bn + wc * (16 * WN) + ni * 16 + lr;
            if (col < Nc) {
                int row = tm + wr * (16 * WM) + mi * 16 + (ln >> 4) * 4;
                #pragma unroll
                for (int r = 0; r < 4; ++r)
                    C[(size_t)(row + r) * ldc + col] = acc[mi][ni][r];
            }
        }
    }
}

// ---------------------------------------------------------------------------
// casts
// ---------------------------------------------------------------------------
__global__ __launch_bounds__(256) void cast_f16_kernel(const float* __restrict__ src,
                                                       _Float16* __restrict__ dst, int n8) {
    int i = blockIdx.x * 256 + threadIdx.x;
    if (i >= n8) return;
    float4 a = ((const float4*)src)[2 * i];
    float4 b = ((const float4*)src)[2 * i + 1];
    half8 h;
    h[0] = (_Float16)a.x; h[1] = (_Float16)a.y; h[2] = (_Float16)a.z; h[3] = (_Float16)a.w;
    h[4] = (_Float16)b.x; h[5] = (_Float16)b.y; h[6] = (_Float16)b.z; h[7] = (_Float16)b.w;
    ((half8*)dst)[i] = h;
}

__global__ __launch_bounds__(256) void cast_pad_f16_kernel(const float* __restrict__ src,
                                                           _Float16* __restrict__ dst,
                                                           int srcRows, int cols, int n8) {
    int i = blockIdx.x * 256 + threadIdx.x;
    if (i >= n8) return;
    int row = (i * 8) / cols;
    half8 h;
    if (row < srcRows) {
        float4 a = ((const float4*)src)[2 * i];
        float4 b = ((const float4*)src)[2 * i + 1];
        h[0] = (_Float16)a.x; h[1] = (_Float16)a.y; h[2] = (_Float16)a.z; h[3] = (_Float16)a.w;
        h[4] = (_Float16)b.x; h[5] = (_Float16)b.y; h[6] = (_Float16)b.z; h[7] = (_Float16)b.w;
    } else {
        #pragma unroll
        for (int q = 0; q < 8; ++q) h[q] = (_Float16)0.f;
    }
    ((half8*)dst)[i] = h;
}

// ---------------------------------------------------------------------------
// Conv + SiLU, tiled with LDS transpose. Block = (bc, 64-channel group).
// Emits f16 xbc [m][c], and coalesced transposed xTg [bc*2048+c][l] (c<2048),
// BTg [bc*128+n][l] (2048<=c<2176). All global stores are >=32B contiguous.
// ---------------------------------------------------------------------------
__global__ __launch_bounds__(256) void conv_silu_kernel(const float* __restrict__ zx,
                                                        const float* __restrict__ conv_w,
                                                        const float* __restrict__ conv_b,
                                                        _Float16* __restrict__ xbc,
                                                        _Float16* __restrict__ xTg,
                                                        _Float16* __restrict__ BTg) {
    __shared__ float zs[67 * 64];
    __shared__ float os[64 * 65];
    const int bid = blockIdx.x;
    const int cg = bid % 36;             // channel group
    const int bc = bid / 36;             // b*8 + chunk
    const int b = bc >> 3, cloc = bc & 7;
    const int c0 = cg * 64;
    const int t = threadIdx.x;

    // per-thread conv weights for compute phase (c = t&63)
    const int cc = c0 + (t & 63);
    const float w0 = conv_w[cc * 4 + 0], w1 = conv_w[cc * 4 + 1];
    const float w2 = conv_w[cc * 4 + 2], w3 = conv_w[cc * 4 + 3];
    const float bias = conv_b[cc];

    for (int lt = 0; lt < 4; ++lt) {
        const int lbase = cloc * 256 + lt * 64;      // within-batch seq pos of l=0
        __syncthreads();                              // protect zs/os reuse
        // load zs[67][64]: rows lbase-3 .. lbase+63
        for (int i = t; i < 67 * 64; i += 256) {
            int r = i >> 6, col = i & 63;
            int lseq = lbase - 3 + r;
            float v = 0.f;
            if (lseq >= 0)
                v = zx[((size_t)(b * SEQ + lseq)) * DINPROJ + DSSM + c0 + col];
            zs[i] = v;
        }
        __syncthreads();
        // compute conv + silu into os[64][65]
        {
            int c = t & 63;
            int w = t >> 6;
            #pragma unroll
            for (int j = 0; j < 16; ++j) {
                int l = w * 16 + j;
                float acc = bias + zs[(l + 0) * 64 + c] * w0 + zs[(l + 1) * 64 + c] * w1
                                 + zs[(l + 2) * 64 + c] * w2 + zs[(l + 3) * 64 + c] * w3;
                os[l * 65 + c] = acc / (1.f + expf(-acc));
            }
        }
        __syncthreads();
        // write xbc rows: thread t -> l = t>>2, cols (t&3)*16 + [0,16)
        {
            int l = t >> 2, cs = (t & 3) * 16;
            size_t m = (size_t)(b * SEQ + lbase + l);
            half8 h0, h1;
            #pragma unroll
            for (int i = 0; i < 8; ++i) h0[i] = (_Float16)os[l * 65 + cs + i];
            #pragma unroll
            for (int i = 0; i < 8; ++i) h1[i] = (_Float16)os[l * 65 + cs + 8 + i];
            _Float16* dst = xbc + m * CONVDIM + c0 + cs;
            *(half8*)dst = h0;
            *(half8*)(dst + 8) = h1;
        }
        // transposed write (only channels < 2176): thread t -> c = t>>2, l-seg (t&3)*16
        if (c0 < CBASE) {
            int c = t >> 2, ls = (t & 3) * 16;
            int gc = c0 + c;
            half8 h0, h1;
            #pragma unroll
            for (int i = 0; i < 8; ++i) h0[i] = (_Float16)os[(ls + i) * 65 + c];
            #pragma unroll
            for (int i = 0; i < 8; ++i) h1[i] = (_Float16)os[(ls + 8 + i) * 65 + c];
            _Float16* dst;
            if (gc < DSSM)
                dst = xTg + ((size_t)bc * 2048 + gc) * 256 + lt * 64 + ls;
            else
                dst = BTg + ((size_t)bc * 128 + (gc - DSSM)) * 256 + lt * 64 + ls;
            *(half8*)dst = h0;
            *(half8*)(dst + 8) = h1;
        }
    }
}

// ---------------------------------------------------------------------------
__global__ __launch_bounds__(256) void dt_kernel(const float* __restrict__ zx,
                                                 const float* __restrict__ dt_bias,
                                                 float* __restrict__ dt) {
    int idx = blockIdx.x * 256 + threadIdx.x;
    if (idx >= ROWS * NHEADS) return;
    int h = idx & 31;
    int m = idx >> 5;
    float v = zx[(size_t)m * DINPROJ + (DSSM + CONVDIM) + h] + dt_bias[h];
    dt[idx] = (v > 20.f) ? v : log1pf(expf(v));
}

__global__ void cumsum_kernel(const float* __restrict__ dt,
                              const float* __restrict__ A_log,
                              float* __restrict__ cum) {
    int t = blockIdx.x * 256 + threadIdx.x;
    if (t >= NBC * NHEADS) return;
    int h = t & 31;
    int bc = t >> 5;
    float A = -expf(A_log[h]);
    float acc = 0.f;
    for (int l = 0; l < CHUNK; ++l) {
        size_t idx = ((size_t)bc * CHUNK + l) * NHEADS + h;
        acc += dt[idx] * A;
        cum[idx] = acc;
    }
}

// ---------------------------------------------------------------------------
// Chunk states via MFMA: S[p][n] = sum_l (coef[l]*x[l,p]) * B[l,n]
// ---------------------------------------------------------------------------
__global__ __launch_bounds__(256) void chunk_state_mfma(const _Float16* __restrict__ xTg,
                                                        const _Float16* __restrict__ BTg,
                                                        const float* __restrict__ dt,
                                                        const float* __restrict__ cum,
                                                        float* __restrict__ S) {
    int bid = blockIdx.x;
    int h = bid & 31, bc = bid >> 5;
    __shared__ _Float16 cxs[64 * 64];      // [p][l-tile], swizzled
    __shared__ _Float16 bts[128 * 64];     // [n][l-tile], swizzled
    __shared__ float coefL[256];
    const int t = threadIdx.x, w = t >> 6, ln = t & 63;
    const int lr = ln & 15, lg = ln >> 4;

    {
        float cl = cum[((size_t)bc * 256 + 255) * 32 + h];
        size_t ci = ((size_t)bc * 256 + t) * 32 + h;
        coefL[t] = expf(cl - cum[ci]) * dt[ci];
    }

    f32x4 sacc[4][2];
    #pragma unroll
    for (int pi = 0; pi < 4; ++pi)
        #pragma unroll
        for (int ni = 0; ni < 2; ++ni) { f32x4 z = {0.f,0.f,0.f,0.f}; sacc[pi][ni] = z; }

    const _Float16* xTh = xTg + (size_t)bid * 64 * 256;   // bid = bc*32+h rows of 64p

    for (int kt = 0; kt < 4; ++kt) {
        __syncthreads();
        {
            int p = t >> 2, l0 = (t & 3) * 16;
            const _Float16* src = xTh + (size_t)p * 256 + kt * 64;
            #pragma unroll
            for (int q = 0; q < 2; ++q) {
                int c = l0 + q * 8;
                half8 hv = *(const half8*)(src + c);
                half8 ov;
                #pragma unroll
                for (int j = 0; j < 8; ++j)
                    ov[j] = (_Float16)((float)hv[j] * coefL[kt * 64 + c + j]);
                *(half8*)(cxs + p * 64 + (c ^ ((p & 7) << 3))) = ov;
            }
        }
        #pragma unroll
        for (int q = 0; q < 4; ++q) {
            int seg = w * 4 + q;
            int r = seg * 8 + (ln >> 3);
            int csw = 8 * ((ln & 7) ^ (r & 7));
            const _Float16* src = BTg + ((size_t)bc * 128 + r) * 256 + kt * 64 + csw;
            gload_lds16(src, (void*)(bts + seg * 512));
        }
        __syncthreads();
        #pragma unroll
        for (int kk = 0; kk < 2; ++kk) {
            int c0 = kk * 32 + lg * 8;
            half8 ax[4], bx[2];
            #pragma unroll
            for (int pi = 0; pi < 4; ++pi) {
                int r = pi * 16 + lr;
                ax[pi] = *(const half8*)(cxs + r * 64 + (c0 ^ ((r & 7) << 3)));
            }
            #pragma unroll
            for (int ni = 0; ni < 2; ++ni) {
                int r = w * 32 + ni * 16 + lr;
                bx[ni] = *(const half8*)(bts + r * 64 + (c0 ^ ((r & 7) << 3)));
            }
            #pragma unroll
            for (int pi = 0; pi < 4; ++pi)
                #pragma unroll
                for (int ni = 0; ni < 2; ++ni)
                    sacc[pi][ni] = __builtin_amdgcn_mfma_f32_16x16x32_f16(ax[pi], bx[ni], sacc[pi][ni], 0, 0, 0);
        }
    }
    float* sb = S + (size_t)bid * (DHEAD * DSTATE);
    #pragma unroll
    for (int pi = 0; pi < 4; ++pi)
        #pragma unroll
        for (int ni = 0; ni < 2; ++ni)
            #pragma unroll
            for (int r = 0; r < 4; ++r) {
                int p = pi * 16 + lg * 4 + r;
                int n = w * 32 + ni * 16 + lr;
                sb[p * 128 + n] = sacc[pi][ni][r];
            }
}

// ---------------------------------------------------------------------------
// Inter-chunk scan; S[c] <- state ENTERING chunk c.
// ---------------------------------------------------------------------------
__global__ __launch_bounds__(256) void scan_kernel(const float* __restrict__ cum,
                                                   float* __restrict__ S) {
    int bid = blockIdx.x;            // b*32 + h
    int h = bid & 31, b = bid >> 5;
    int t = threadIdx.x;
    float carry[32];
    #pragma unroll
    for (int i = 0; i < 32; ++i) carry[i] = 0.f;
    for (int c = 0; c < NCHUNK; ++c) {
        int bc = b * NCHUNK + c;
        float decay = expf(cum[((size_t)bc * CHUNK + 255) * NHEADS + h]);
        size_t base = ((size_t)(bc * NHEADS + h)) * (DHEAD * DSTATE);
        #pragma unroll
        for (int i = 0; i < 32; ++i) {
            size_t idx = base + t + i * 256;
            float s = S[idx];
            float nw = carry[i] * decay + s;
            S[idx] = carry[i];
            carry[i] = nw;
        }
    }
}

// ---------------------------------------------------------------------------
// Y via MFMA: inter = mfma(C, prev); intra = mfma(C,B) -> P -> mfma(P, xT).
// ---------------------------------------------------------------------------
__global__ __launch_bounds__(256) void y_mfma(const _Float16* __restrict__ xbc,
                                              const _Float16* __restrict__ xTg,
                                              const float* __restrict__ dt,
                                              const float* __restrict__ cum,
                                              const float* __restrict__ Sprev,
                                              const float* __restrict__ Dp,
                                              float* __restrict__ y) {
    int bid = blockIdx.x;
    int h = bid & 31, bc = bid >> 5;
    __shared__ _Float16 prevh[64 * 128];   // [p][n], swizzled
    __shared__ _Float16 Bs[64 * 128];      // [s][n], swizzled
    __shared__ _Float16 xTs[64 * 64];      // [p][s-tile], swizzled
    __shared__ _Float16 Pw[4 * 64 * 64];   // per-wave P [l][s], swizzled
    __shared__ float cumL[256], dtL[256];
    const int t = threadIdx.x, w = t >> 6, ln = t & 63;
    const int lr = ln & 15, lg = ln >> 4;

    {
        size_t ci = ((size_t)bc * 256 + t) * 32 + h;
        cumL[t] = cum[ci];
        dtL[t]  = dt[ci];
    }
    {
        const float* sp = Sprev + (size_t)bid * (DHEAD * DSTATE);
        int r = t >> 2, c0 = (t & 3) * 32;
        #pragma unroll
        for (int q = 0; q < 4; ++q) {
            int c = c0 + q * 8;
            float4 f0 = *(const float4*)(sp + r * 128 + c);
            float4 f1 = *(const float4*)(sp + r * 128 + c + 4);
            half8 hv;
            hv[0]=(_Float16)f0.x; hv[1]=(_Float16)f0.y; hv[2]=(_Float16)f0.z; hv[3]=(_Float16)f0.w;
            hv[4]=(_Float16)f1.x; hv[5]=(_Float16)f1.y; hv[6]=(_Float16)f1.z; hv[7]=(_Float16)f1.w;
            *(half8*)(prevh + r * 128 + (c ^ ((r & 7) << 3))) = hv;
        }
    }
    half8 ca[4][4];
    {
        const _Float16* cb = xbc + ((size_t)(bc * 256 + w * 64)) * CONVDIM + CBASE;
        #pragma unroll
        for (int mi = 0; mi < 4; ++mi)
            #pragma unroll
            for (int kk = 0; kk < 4; ++kk)
                ca[mi][kk] = *(const half8*)(cb + (size_t)(mi * 16 + lr) * CONVDIM + kk * 32 + lg * 8);
    }
    __syncthreads();

    f32x4 yacc[4][4];
    #pragma unroll
    for (int i = 0; i < 4; ++i)
        #pragma unroll
        for (int j = 0; j < 4; ++j) { f32x4 z = {0.f,0.f,0.f,0.f}; yacc[i][j] = z; }

    #pragma unroll
    for (int kk = 0; kk < 4; ++kk) {
        int c0 = kk * 32 + lg * 8;
        #pragma unroll
        for (int pi = 0; pi < 4; ++pi) {
            int r = pi * 16 + lr;
            half8 pb = *(const half8*)(prevh + r * 128 + (c0 ^ ((r & 7) << 3)));
            #pragma unroll
            for (int mi = 0; mi < 4; ++mi)
                yacc[mi][pi] = __builtin_amdgcn_mfma_f32_16x16x32_f16(ca[mi][kk], pb, yacc[mi][pi], 0, 0, 0);
        }
    }
    #pragma unroll
    for (int mi = 0; mi < 4; ++mi)
        #pragma unroll
        for (int r = 0; r < 4; ++r) {
            float el = expf(cumL[w * 64 + mi * 16 + lg * 4 + r]);
            #pragma unroll
            for (int pi = 0; pi < 4; ++pi) yacc[mi][pi][r] *= el;
        }

    for (int st = 0; st < 4; ++st) {
        __syncthreads();
        #pragma unroll
        for (int q = 0; q < 4; ++q) {
            int seg = w * 4 + q;
            int r = seg * 4 + lg;
            int csw = 8 * (lr ^ (r & 7));
            const _Float16* src = xbc + ((size_t)(bc * 256 + st * 64 + r)) * CONVDIM + DSSM + csw;
            gload_lds16(src, (void*)(Bs + seg * 512));
        }
        #pragma unroll
        for (int q = 0; q < 2; ++q) {
            int seg = w * 2 + q;
            int r = seg * 8 + (ln >> 3);
            int csw = 8 * ((ln & 7) ^ (r & 7));
            const _Float16* src = xTg + ((size_t)bid * 64 + r) * 256 + st * 64 + csw;
            gload_lds16(src, (void*)(xTs + seg * 512));
        }
        __syncthreads();
        if (st <= w) {
            f32x4 pacc[4][4];
            #pragma unroll
            for (int i = 0; i < 4; ++i)
                #pragma unroll
                for (int j = 0; j < 4; ++j) { f32x4 z = {0.f,0.f,0.f,0.f}; pacc[i][j] = z; }
            #pragma unroll
            for (int kk = 0; kk < 4; ++kk) {
                int c0 = kk * 32 + lg * 8;
                #pragma unroll
                for (int si = 0; si < 4; ++si) {
                    int r = si * 16 + lr;
                    half8 bb = *(const half8*)(Bs + r * 128 + (c0 ^ ((r & 7) << 3)));
                    #pragma unroll
                    for (int mi = 0; mi < 4; ++mi)
                        pacc[mi][si] = __builtin_amdgcn_mfma_f32_16x16x32_f16(ca[mi][kk], bb, pacc[mi][si], 0, 0, 0);
                }
            }
            _Float16* pwb = Pw + w * 4096;
            bool diag = (st == w);
            #pragma unroll
            for (int mi = 0; mi < 4; ++mi) {
                #pragma unroll
                for (int r = 0; r < 4; ++r) {
                    int lloc = mi * 16 + lg * 4 + r;
                    float cl = cumL[w * 64 + lloc];
                    #pragma unroll
                    for (int si = 0; si < 4; ++si) {
                        int scol = si * 16 + lr;
                        int s = st * 64 + scol;
                        float v = 0.f;
                        if (!diag || s <= (w * 64 + lloc))
                            v = pacc[mi][si][r] * expf(cl - cumL[s]) * dtL[s];
                        pwb[lloc * 64 + (scol ^ ((lloc & 7) << 3))] = (_Float16)v;
                    }
                }
            }
            #pragma unroll
            for (int kk2 = 0; kk2 < 2; ++kk2) {
                int c0 = kk2 * 32 + lg * 8;
                half8 pa[4];
                #pragma unroll
                for (int mi = 0; mi < 4; ++mi) {
                    int r = mi * 16 + lr;
                    pa[mi] = *(const half8*)(pwb + r * 64 + (c0 ^ ((r & 7) << 3)));
                }
                #pragma unroll
                for (int pi = 0; pi < 4; ++pi) {
                    int r = pi * 16 + lr;
                    half8 xb = *(const half8*)(xTs + r * 64 + (c0 ^ ((r & 7) << 3)));
                    #pragma unroll
                    for (int mi = 0; mi < 4; ++mi)
                        yacc[mi][pi] = __builtin_amdgcn_mfma_f32_16x16x32_f16(pa[mi], xb, yacc[mi][pi], 0, 0, 0);
                }
            }
        }
    }

    float dv = Dp[h];
    #pragma unroll
    for (int mi = 0; mi < 4; ++mi) {
        #pragma unroll
        for (int r = 0; r < 4; ++r) {
            int l = w * 64 + mi * 16 + lg * 4 + r;
            size_t row = (size_t)bc * 256 + l;
            #pragma unroll
            for (int pi = 0; pi < 4; ++pi) {
                int p = pi * 16 + lr;
                float xv = (float)xbc[row * CONVDIM + h * 64 + p];
                y[row * DSSM + h * 64 + p] = yacc[mi][pi][r] + dv * xv;
            }
        }
    }
}

// ---------------------------------------------------------------------------
// Gated RMSNorm -> f16 output for out_proj MFMA
// ---------------------------------------------------------------------------
__global__ __launch_bounds__(256) void norm_kernel(const float* __restrict__ y,
                                                   const float* __restrict__ zx,
                                                   const float* __restrict__ norm_w,
                                                   _Float16* __restrict__ outh) {
    int m = blockIdx.x;
    int t = threadIdx.x;
    const float* yrow = y + (size_t)m * DSSM;
    const float* zrow = zx + (size_t)m * DINPROJ;
    float yg[8];
    float ss = 0.f;
    #pragma unroll
    for (int q = 0; q < 2; ++q) {
        float4 yv = *(const float4*)(yrow + t*8 + q*4);
        float4 zv = *(const float4*)(zrow + t*8 + q*4);
        float zvals[4] = {zv.x, zv.y, zv.z, zv.w};
        float yvals[4] = {yv.x, yv.y, yv.z, yv.w};
        #pragma unroll
        for (int i = 0; i < 4; ++i) {
            float sz = zvals[i] / (1.f + expf(-zvals[i]));
            float g = yvals[i] * sz;
            yg[q*4+i] = g;
            ss += g * g;
        }
    }
    #pragma unroll
    for (int off = 32; off > 0; off >>= 1) ss += __shfl_xor(ss, off, 64);
    __shared__ float red[4];
    if ((t & 63) == 0) red[t >> 6] = ss;
    __syncthreads();
    float tot = red[0] + red[1] + red[2] + red[3];
    float inv = rsqrtf(tot / (float)DSSM + EPSF);
    half8 h;
    #pragma unroll
    for (int q = 0; q < 8; ++q)
        h[q] = (_Float16)(yg[q] * inv * norm_w[t*8 + q]);
    *(half8*)(outh + (size_t)m * DSSM + t * 8) = h;
}

// ---------------------------------------------------------------------------
extern "C" void kernel_launch(void* const* d_in, const int* in_sizes, int n_in,
                              void* d_out, int out_size, void* d_ws, size_t ws_size,
                              hipStream_t stream) {
    (void)in_sizes; (void)n_in; (void)out_size; (void)ws_size;
    const float* u       = (const float*)d_in[0];
    const float* W_in    = (const float*)d_in[1];
    const float* conv_w  = (const float*)d_in[2];
    const float* conv_b  = (const float*)d_in[3];
    const float* dt_bias = (const float*)d_in[4];
    const float* A_log   = (const float*)d_in[5];
    const float* Dp      = (const float*)d_in[6];
    const float* norm_w  = (const float*)d_in[7];
    const float* W_out   = (const float*)d_in[8];
    float* out = (float*)d_out;

    // workspace layout
    float* zx   = (float*)d_ws;                       // ROWS*DINPROJ
    float* dtb  = zx   + (size_t)ROWS * DINPROJ;      // ROWS*NHEADS
    float* cum  = dtb  + (size_t)ROWS * NHEADS;
    float* Sbuf = cum  + (size_t)ROWS * NHEADS;       // 512*64*128
    float* yb   = Sbuf + (size_t)NBC * NHEADS * DHEAD * DSTATE;  // ROWS*DSSM
    _Float16* xbc_h = (_Float16*)(yb + (size_t)ROWS * DSSM);     // ROWS*CONVDIM
    _Float16* xTg   = xbc_h + (size_t)ROWS * CONVDIM;            // 512*64*256
    _Float16* BTg   = xTg   + (size_t)NBC * NHEADS * 64 * 256;   // 16*128*256
    _Float16* uh    = BTg   + (size_t)NBC * 128 * 256;
    _Float16* Wih   = uh    + (size_t)ROWS * DMODEL;
    _Float16* Wouth = Wih   + (size_t)NPAD * DMODEL;
    _Float16* ybh   = Wouth + (size_t)DMODEL * DSSM;

    // casts
    cast_f16_kernel<<<(ROWS * DMODEL / 8 + 255) / 256, 256, 0, stream>>>(u, uh, ROWS * DMODEL / 8);
    cast_pad_f16_kernel<<<(NPAD * DMODEL / 8 + 255) / 256, 256, 0, stream>>>(
        W_in, Wih, DINPROJ, DMODEL, NPAD * DMODEL / 8);
    cast_f16_kernel<<<(DMODEL * DSSM / 8 + 255) / 256, 256, 0, stream>>>(W_out, Wouth, DMODEL * DSSM / 8);

    // 1. in_proj
    gemm_f16<4, 4><<<dim3(NPAD / 128, ROWS / 128), 256, 0, stream>>>(
        uh, Wih, zx, DMODEL, DINPROJ, DINPROJ);
    // 2. conv + silu -> f16 xbc + transposed copies (tiled, coalesced)
    conv_silu_kernel<<<NBC * 36, 256, 0, stream>>>(
        zx, conv_w, conv_b, xbc_h, xTg, BTg);
    // 3. dt
    dt_kernel<<<(ROWS * NHEADS + 255) / 256, 256, 0, stream>>>(zx, dt_bias, dtb);
    // 4. cumsum
    cumsum_kernel<<<2, 256, 0, stream>>>(dtb, A_log, cum);
    // 5. chunk states (MFMA)
    chunk_state_mfma<<<NBC * NHEADS, 256, 0, stream>>>(xTg, BTg, dtb, cum, Sbuf);
    // 6. inter-chunk scan
    scan_kernel<<<BATCH * NHEADS, 256, 0, stream>>>(cum, Sbuf);
    // 7. Y (MFMA)
    y_mfma<<<NBC * NHEADS, 256, 0, stream>>>(xbc_h, xTg, dtb, cum, Sbuf, Dp, yb);
    // 8. gated RMSNorm -> f16
    norm_kernel<<<ROWS, 256, 0, stream>>>(yb, zx, norm_w, ybh);
    // 9. out_proj
    gemm_f16<4, 2><<<dim3(DMODEL / 64, ROWS / 128), 256, 0, stream>>>(
        ybh, Wouth, out, DSSM, DMODEL, DMODEL);
}

// Round 5
// 320.044 us; speedup vs baseline: 6.4347x; 1.1608x over previous
//
#include <hip/hip_runtime.h>
#include <hip/hip_bf16.h>
#include <math.h>
#include <stdint.h>

// Problem constants
#define BATCH    2
#define SEQ      2048
#define DMODEL   1024
#define DSSM     2048
#define NHEADS   32
#define DHEAD    64
#define DSTATE   128
#define CONVDIM  2304     // DSSM + 2*DSTATE
#define DINPROJ  4384     // 2*2048 + 2*128 + 32
#define NPAD     4480     // DINPROJ padded to multiple of 128
#define CHUNK    256
#define NCHUNK   8
#define ROWS     (BATCH*SEQ)          // 4096
#define NBC      (BATCH*NCHUNK)       // 16
#define EPSF     1e-5f
#define CBASE    (DSSM + DSTATE)      // 2176, C columns in xbc

typedef _Float16 half8 __attribute__((ext_vector_type(8)));
typedef _Float16 half4 __attribute__((ext_vector_type(4)));
typedef float f32x4 __attribute__((ext_vector_type(4)));

// global_load_lds: 16B per lane, LDS dest = wave-uniform base + lane*16
static __device__ __forceinline__ void gload_lds16(const void* g, void* l) {
    __builtin_amdgcn_global_load_lds(
        (const __attribute__((address_space(1))) uint32_t*)g,
        (__attribute__((address_space(3))) uint32_t*)l, 16, 0, 0);
}

// ---------------------------------------------------------------------------
// MFMA GEMM (f16 in, f32 out): C[M,N] = A[M,K] * B[N,K]^T.  BK=64,
// XOR-swizzled LDS (pre-swizzled global source, swizzled frag reads).
// ---------------------------------------------------------------------------
template<int WM, int WN>
__global__ __launch_bounds__(256) void gemm_f16(const _Float16* __restrict__ A,
                                                const _Float16* __restrict__ B,
                                                float* __restrict__ C,
                                                int K, int ldc, int Nc) {
    constexpr int BM = 32 * WM;
    constexpr int BN = 32 * WN;
    __shared__ _Float16 As[BM * 64];
    __shared__ _Float16 Bs[BN * 64];
    const int t  = threadIdx.x;
    const int wv = t >> 6;
    const int ln = t & 63;
    const int wr = wv >> 1, wc = wv & 1;
    const int tm = blockIdx.y * BM;
    const int bn = blockIdx.x * BN;
    const int kb = ln >> 4;          // 0..3 : which 8-k slice within a 32-k half
    const int lr = ln & 15;
    const int srow = ln >> 3;        // stage: row within 8-row segment
    const int susw = (ln & 7) ^ srow; // stage: pre-swizzled source col-unit

    f32x4 acc[WM][WN];
    #pragma unroll
    for (int i = 0; i < WM; ++i)
        #pragma unroll
        for (int j = 0; j < WN; ++j) { f32x4 z = {0.f, 0.f, 0.f, 0.f}; acc[i][j] = z; }

    for (int k0 = 0; k0 < K; k0 += 64) {
        #pragma unroll
        for (int q = 0; q < BM / 32; ++q) {
            int seg = q * 4 + wv;                  // 8 rows per segment
            int row = seg * 8 + srow;
            const _Float16* src = A + (size_t)(tm + row) * K + k0 + susw * 8;
            gload_lds16(src, (void*)(As + seg * 512));
        }
        #pragma unroll
        for (int q = 0; q < BN / 32; ++q) {
            int seg = q * 4 + wv;
            int row = seg * 8 + srow;
            const _Float16* src = B + (size_t)(bn + row) * K + k0 + susw * 8;
            gload_lds16(src, (void*)(Bs + seg * 512));
        }
        __syncthreads();

        #pragma unroll
        for (int ks = 0; ks < 2; ++ks) {
            half8 af[WM], bf[WN];
            #pragma unroll
            for (int mi = 0; mi < WM; ++mi) {
                int r = wr * (16 * WM) + mi * 16 + lr;
                af[mi] = *(const half8*)(As + r * 64 + (((ks * 4 + kb) ^ (r & 7)) << 3));
            }
            #pragma unroll
            for (int ni = 0; ni < WN; ++ni) {
                int r = wc * (16 * WN) + ni * 16 + lr;
                bf[ni] = *(const half8*)(Bs + r * 64 + (((ks * 4 + kb) ^ (r & 7)) << 3));
            }
            #pragma unroll
            for (int mi = 0; mi < WM; ++mi)
                #pragma unroll
                for (int ni = 0; ni < WN; ++ni)
                    acc[mi][ni] = __builtin_amdgcn_mfma_f32_16x16x32_f16(af[mi], bf[ni], acc[mi][ni], 0, 0, 0);
        }
        __syncthreads();
    }

    #pragma unroll
    for (int mi = 0; mi < WM; ++mi) {
        #pragma unroll
        for (int ni = 0; ni < WN; ++ni) {
            int col = bn + wc * (16 * WN) + ni * 16 + lr;
            if (col < Nc) {
                int row = tm + wr * (16 * WM) + mi * 16 + (ln >> 4) * 4;
                #pragma unroll
                for (int r = 0; r < 4; ++r)
                    C[(size_t)(row + r) * ldc + col] = acc[mi][ni][r];
            }
        }
    }
}

// ---------------------------------------------------------------------------
// casts
// ---------------------------------------------------------------------------
__global__ __launch_bounds__(256) void cast_f16_kernel(const float* __restrict__ src,
                                                       _Float16* __restrict__ dst, int n8) {
    int i = blockIdx.x * 256 + threadIdx.x;
    if (i >= n8) return;
    float4 a = ((const float4*)src)[2 * i];
    float4 b = ((const float4*)src)[2 * i + 1];
    half8 h;
    h[0] = (_Float16)a.x; h[1] = (_Float16)a.y; h[2] = (_Float16)a.z; h[3] = (_Float16)a.w;
    h[4] = (_Float16)b.x; h[5] = (_Float16)b.y; h[6] = (_Float16)b.z; h[7] = (_Float16)b.w;
    ((half8*)dst)[i] = h;
}

__global__ __launch_bounds__(256) void cast_pad_f16_kernel(const float* __restrict__ src,
                                                           _Float16* __restrict__ dst,
                                                           int srcRows, int cols, int n8) {
    int i = blockIdx.x * 256 + threadIdx.x;
    if (i >= n8) return;
    int row = (i * 8) / cols;
    half8 h;
    if (row < srcRows) {
        float4 a = ((const float4*)src)[2 * i];
        float4 b = ((const float4*)src)[2 * i + 1];
        h[0] = (_Float16)a.x; h[1] = (_Float16)a.y; h[2] = (_Float16)a.z; h[3] = (_Float16)a.w;
        h[4] = (_Float16)b.x; h[5] = (_Float16)b.y; h[6] = (_Float16)b.z; h[7] = (_Float16)b.w;
    } else {
        #pragma unroll
        for (int q = 0; q < 8; ++q) h[q] = (_Float16)0.f;
    }
    ((half8*)dst)[i] = h;
}

// ---------------------------------------------------------------------------
// Conv + SiLU, tiled with LDS transpose (coalesced dual-layout outputs).
// ---------------------------------------------------------------------------
__global__ __launch_bounds__(256) void conv_silu_kernel(const float* __restrict__ zx,
                                                        const float* __restrict__ conv_w,
                                                        const float* __restrict__ conv_b,
                                                        _Float16* __restrict__ xbc,
                                                        _Float16* __restrict__ xTg,
                                                        _Float16* __restrict__ BTg) {
    __shared__ float zs[67 * 64];
    __shared__ float os[64 * 65];
    const int bid = blockIdx.x;
    const int cg = bid % 36;             // channel group
    const int bc = bid / 36;             // b*8 + chunk
    const int b = bc >> 3, cloc = bc & 7;
    const int c0 = cg * 64;
    const int t = threadIdx.x;

    const int cc = c0 + (t & 63);
    const float w0 = conv_w[cc * 4 + 0], w1 = conv_w[cc * 4 + 1];
    const float w2 = conv_w[cc * 4 + 2], w3 = conv_w[cc * 4 + 3];
    const float bias = conv_b[cc];

    for (int lt = 0; lt < 4; ++lt) {
        const int lbase = cloc * 256 + lt * 64;
        __syncthreads();
        for (int i = t; i < 67 * 64; i += 256) {
            int r = i >> 6, col = i & 63;
            int lseq = lbase - 3 + r;
            float v = 0.f;
            if (lseq >= 0)
                v = zx[((size_t)(b * SEQ + lseq)) * DINPROJ + DSSM + c0 + col];
            zs[i] = v;
        }
        __syncthreads();
        {
            int c = t & 63;
            int w = t >> 6;
            #pragma unroll
            for (int j = 0; j < 16; ++j) {
                int l = w * 16 + j;
                float acc = bias + zs[(l + 0) * 64 + c] * w0 + zs[(l + 1) * 64 + c] * w1
                                 + zs[(l + 2) * 64 + c] * w2 + zs[(l + 3) * 64 + c] * w3;
                os[l * 65 + c] = acc / (1.f + expf(-acc));
            }
        }
        __syncthreads();
        {
            int l = t >> 2, cs = (t & 3) * 16;
            size_t m = (size_t)(b * SEQ + lbase + l);
            half8 h0, h1;
            #pragma unroll
            for (int i = 0; i < 8; ++i) h0[i] = (_Float16)os[l * 65 + cs + i];
            #pragma unroll
            for (int i = 0; i < 8; ++i) h1[i] = (_Float16)os[l * 65 + cs + 8 + i];
            _Float16* dst = xbc + m * CONVDIM + c0 + cs;
            *(half8*)dst = h0;
            *(half8*)(dst + 8) = h1;
        }
        if (c0 < CBASE) {
            int c = t >> 2, ls = (t & 3) * 16;
            int gc = c0 + c;
            half8 h0, h1;
            #pragma unroll
            for (int i = 0; i < 8; ++i) h0[i] = (_Float16)os[(ls + i) * 65 + c];
            #pragma unroll
            for (int i = 0; i < 8; ++i) h1[i] = (_Float16)os[(ls + 8 + i) * 65 + c];
            _Float16* dst;
            if (gc < DSSM)
                dst = xTg + ((size_t)bc * 2048 + gc) * 256 + lt * 64 + ls;
            else
                dst = BTg + ((size_t)bc * 128 + (gc - DSSM)) * 256 + lt * 64 + ls;
            *(half8*)dst = h0;
            *(half8*)(dst + 8) = h1;
        }
    }
}

// ---------------------------------------------------------------------------
__global__ __launch_bounds__(256) void dt_kernel(const float* __restrict__ zx,
                                                 const float* __restrict__ dt_bias,
                                                 float* __restrict__ dt) {
    int idx = blockIdx.x * 256 + threadIdx.x;
    if (idx >= ROWS * NHEADS) return;
    int h = idx & 31;
    int m = idx >> 5;
    float v = zx[(size_t)m * DINPROJ + (DSSM + CONVDIM) + h] + dt_bias[h];
    dt[idx] = (v > 20.f) ? v : log1pf(expf(v));
}

__global__ void cumsum_kernel(const float* __restrict__ dt,
                              const float* __restrict__ A_log,
                              float* __restrict__ cum) {
    int t = blockIdx.x * 256 + threadIdx.x;
    if (t >= NBC * NHEADS) return;
    int h = t & 31;
    int bc = t >> 5;
    float A = -expf(A_log[h]);
    float acc = 0.f;
    for (int l = 0; l < CHUNK; ++l) {
        size_t idx = ((size_t)bc * CHUNK + l) * NHEADS + h;
        acc += dt[idx] * A;
        cum[idx] = acc;
    }
}

// ---------------------------------------------------------------------------
// Chunk states via MFMA: S[p][n] = sum_l (coef[l]*x[l,p]) * B[l,n]
// ---------------------------------------------------------------------------
__global__ __launch_bounds__(256) void chunk_state_mfma(const _Float16* __restrict__ xTg,
                                                        const _Float16* __restrict__ BTg,
                                                        const float* __restrict__ dt,
                                                        const float* __restrict__ cum,
                                                        float* __restrict__ S) {
    int bid = blockIdx.x;
    int h = bid & 31, bc = bid >> 5;
    __shared__ _Float16 cxs[64 * 64];      // [p][l-tile], swizzled
    __shared__ _Float16 bts[128 * 64];     // [n][l-tile], swizzled
    __shared__ float coefL[256];
    const int t = threadIdx.x, w = t >> 6, ln = t & 63;
    const int lr = ln & 15, lg = ln >> 4;

    {
        float cl = cum[((size_t)bc * 256 + 255) * 32 + h];
        size_t ci = ((size_t)bc * 256 + t) * 32 + h;
        coefL[t] = expf(cl - cum[ci]) * dt[ci];
    }

    f32x4 sacc[4][2];
    #pragma unroll
    for (int pi = 0; pi < 4; ++pi)
        #pragma unroll
        for (int ni = 0; ni < 2; ++ni) { f32x4 z = {0.f,0.f,0.f,0.f}; sacc[pi][ni] = z; }

    const _Float16* xTh = xTg + (size_t)bid * 64 * 256;

    for (int kt = 0; kt < 4; ++kt) {
        __syncthreads();
        {
            int p = t >> 2, l0 = (t & 3) * 16;
            const _Float16* src = xTh + (size_t)p * 256 + kt * 64;
            #pragma unroll
            for (int q = 0; q < 2; ++q) {
                int c = l0 + q * 8;
                half8 hv = *(const half8*)(src + c);
                half8 ov;
                #pragma unroll
                for (int j = 0; j < 8; ++j)
                    ov[j] = (_Float16)((float)hv[j] * coefL[kt * 64 + c + j]);
                *(half8*)(cxs + p * 64 + (c ^ ((p & 7) << 3))) = ov;
            }
        }
        #pragma unroll
        for (int q = 0; q < 4; ++q) {
            int seg = w * 4 + q;
            int r = seg * 8 + (ln >> 3);
            int csw = 8 * ((ln & 7) ^ (r & 7));
            const _Float16* src = BTg + ((size_t)bc * 128 + r) * 256 + kt * 64 + csw;
            gload_lds16(src, (void*)(bts + seg * 512));
        }
        __syncthreads();
        #pragma unroll
        for (int kk = 0; kk < 2; ++kk) {
            int c0 = kk * 32 + lg * 8;
            half8 ax[4], bx[2];
            #pragma unroll
            for (int pi = 0; pi < 4; ++pi) {
                int r = pi * 16 + lr;
                ax[pi] = *(const half8*)(cxs + r * 64 + (c0 ^ ((r & 7) << 3)));
            }
            #pragma unroll
            for (int ni = 0; ni < 2; ++ni) {
                int r = w * 32 + ni * 16 + lr;
                bx[ni] = *(const half8*)(bts + r * 64 + (c0 ^ ((r & 7) << 3)));
            }
            #pragma unroll
            for (int pi = 0; pi < 4; ++pi)
                #pragma unroll
                for (int ni = 0; ni < 2; ++ni)
                    sacc[pi][ni] = __builtin_amdgcn_mfma_f32_16x16x32_f16(ax[pi], bx[ni], sacc[pi][ni], 0, 0, 0);
        }
    }
    float* sb = S + (size_t)bid * (DHEAD * DSTATE);
    #pragma unroll
    for (int pi = 0; pi < 4; ++pi)
        #pragma unroll
        for (int ni = 0; ni < 2; ++ni)
            #pragma unroll
            for (int r = 0; r < 4; ++r) {
                int p = pi * 16 + lg * 4 + r;
                int n = w * 32 + ni * 16 + lr;
                sb[p * 128 + n] = sacc[pi][ni][r];
            }
}

// ---------------------------------------------------------------------------
// Inter-chunk scan; S[c] <- state ENTERING chunk c.
// ---------------------------------------------------------------------------
__global__ __launch_bounds__(256) void scan_kernel(const float* __restrict__ cum,
                                                   float* __restrict__ S) {
    int bid = blockIdx.x;            // b*32 + h
    int h = bid & 31, b = bid >> 5;
    int t = threadIdx.x;
    float carry[32];
    #pragma unroll
    for (int i = 0; i < 32; ++i) carry[i] = 0.f;
    for (int c = 0; c < NCHUNK; ++c) {
        int bc = b * NCHUNK + c;
        float decay = expf(cum[((size_t)bc * CHUNK + 255) * NHEADS + h]);
        size_t base = ((size_t)(bc * NHEADS + h)) * (DHEAD * DSTATE);
        #pragma unroll
        for (int i = 0; i < 32; ++i) {
            size_t idx = base + t + i * 256;
            float s = S[idx];
            float nw = carry[i] * decay + s;
            S[idx] = carry[i];
            carry[i] = nw;
        }
    }
}

// ---------------------------------------------------------------------------
// Y via MFMA v2: swapped QK (P^T in regs -> vectorized b64 P writes),
// factored decay, D folded into P diagonal, prev staged into Pw space,
// xT B-frags direct from global, double-buffered Bs, 1 barrier/iter.
// ---------------------------------------------------------------------------
__global__ __launch_bounds__(256, 2) void y_mfma(const _Float16* __restrict__ xbc,
                                                 const _Float16* __restrict__ xTg,
                                                 const float* __restrict__ dt,
                                                 const float* __restrict__ cum,
                                                 const float* __restrict__ Sprev,
                                                 const float* __restrict__ Dp,
                                                 float* __restrict__ y) {
    int bid = blockIdx.x;
    int h = bid & 31, bc = bid >> 5;
    __shared__ _Float16 Bs2[2][64 * 128];  // double-buffered B tile [s][n], swizzled
    __shared__ _Float16 PwF[4 * 64 * 64];  // per-wave P [l][s]; first 16KB doubles as prev[p][n]
    __shared__ float cumL[256], dtL[256];
    const int t = threadIdx.x, w = t >> 6, ln = t & 63;
    const int lr = ln & 15, lg = ln >> 4;

    {
        size_t ci = ((size_t)bc * 256 + t) * 32 + h;
        cumL[t] = cum[ci];
        dtL[t]  = dt[ci];
    }
    // stage prev (f32 -> f16, swizzled rows of 128) into PwF[0..8191]
    {
        const float* sp = Sprev + (size_t)bid * (DHEAD * DSTATE);
        int r = t >> 2, cb = (t & 3) * 32;
        #pragma unroll
        for (int q = 0; q < 4; ++q) {
            int c = cb + q * 8;
            float4 f0 = *(const float4*)(sp + r * 128 + c);
            float4 f1 = *(const float4*)(sp + r * 128 + c + 4);
            half8 hv;
            hv[0]=(_Float16)f0.x; hv[1]=(_Float16)f0.y; hv[2]=(_Float16)f0.z; hv[3]=(_Float16)f0.w;
            hv[4]=(_Float16)f1.x; hv[5]=(_Float16)f1.y; hv[6]=(_Float16)f1.z; hv[7]=(_Float16)f1.w;
            *(half8*)(PwF + r * 128 + (c ^ ((r & 7) << 3))) = hv;
        }
    }
    // stage Bs2[0] for st=0 (pre-swizzled source)
    {
        #pragma unroll
        for (int q = 0; q < 4; ++q) {
            int seg = w * 4 + q;
            int r = seg * 4 + lg;
            int csw = 8 * (lr ^ (r & 7));
            const _Float16* src = xbc + ((size_t)(bc * 256 + r)) * CONVDIM + DSSM + csw;
            gload_lds16(src, (void*)(Bs2[0] + seg * 512));
        }
    }
    // C a-fragments from global (rows l, k = n)
    half8 ca[4][4];
    {
        const _Float16* cb = xbc + ((size_t)(bc * 256 + w * 64)) * CONVDIM + CBASE;
        #pragma unroll
        for (int mi = 0; mi < 4; ++mi)
            #pragma unroll
            for (int kk = 0; kk < 4; ++kk)
                ca[mi][kk] = *(const half8*)(cb + (size_t)(mi * 16 + lr) * CONVDIM + kk * 32 + lg * 8);
    }
    __syncthreads();   // B1: prev + Bs(0) + cum/dt ready

    f32x4 yacc[4][4];
    #pragma unroll
    for (int i = 0; i < 4; ++i)
        #pragma unroll
        for (int j = 0; j < 4; ++j) { f32x4 z = {0.f,0.f,0.f,0.f}; yacc[i][j] = z; }

    // inter-chunk: D[l][p] = sum_n C[l,n]*prev[p,n]
    #pragma unroll
    for (int kk = 0; kk < 4; ++kk) {
        int co = kk * 32 + lg * 8;
        #pragma unroll
        for (int pi = 0; pi < 4; ++pi) {
            int r = pi * 16 + lr;
            half8 pb = *(const half8*)(PwF + r * 128 + (co ^ ((r & 7) << 3)));
            #pragma unroll
            for (int mi = 0; mi < 4; ++mi)
                yacc[mi][pi] = __builtin_amdgcn_mfma_f32_16x16x32_f16(ca[mi][kk], pb, yacc[mi][pi], 0, 0, 0);
        }
    }
    // scale by exp(cum[l])  (yacc row l = mi*16+lg*4+r)
    #pragma unroll
    for (int mi = 0; mi < 4; ++mi)
        #pragma unroll
        for (int r = 0; r < 4; ++r) {
            float e = expf(cumL[w * 64 + mi * 16 + lg * 4 + r]);
            #pragma unroll
            for (int pi = 0; pi < 4; ++pi) yacc[mi][pi][r] *= e;
        }
    // per-wave decay factoring constants (P^T layout: l = mi*16+lr)
    float c0 = cumL[w * 64];
    float el[4];
    #pragma unroll
    for (int mi = 0; mi < 4; ++mi) el[mi] = expf(cumL[w * 64 + mi * 16 + lr] - c0);
    float Dv = Dp[h];

    __syncthreads();   // B2: all inter reads of prev done -> Pw reusable

    _Float16* pwb = PwF + w * 4096;
    for (int st = 0; st < 4; ++st) {
        // prefetch next B tile into the other buffer
        if (st < 3) {
            #pragma unroll
            for (int q = 0; q < 4; ++q) {
                int seg = w * 4 + q;
                int r = seg * 4 + lg;
                int csw = 8 * (lr ^ (r & 7));
                const _Float16* src = xbc + ((size_t)(bc * 256 + (st + 1) * 64 + r)) * CONVDIM + DSSM + csw;
                gload_lds16(src, (void*)(Bs2[(st + 1) & 1] + seg * 512));
            }
        }
        if (st <= w) {
            const _Float16* bsc = Bs2[st & 1];
            // xT B-frags direct from global (L1-served, shared by all 4 waves)
            half8 xb[4][2];
            #pragma unroll
            for (int pi = 0; pi < 4; ++pi)
                #pragma unroll
                for (int k2 = 0; k2 < 2; ++k2)
                    xb[pi][k2] = *(const half8*)(xTg + ((size_t)bid * 64 + pi * 16 + lr) * 256
                                                 + st * 64 + k2 * 32 + lg * 8);
            // QK^T (swapped): pT[s][l], per si slice to bound registers
            #pragma unroll
            for (int si = 0; si < 4; ++si) {
                f32x4 ps[4];
                #pragma unroll
                for (int mi = 0; mi < 4; ++mi) { f32x4 z = {0.f,0.f,0.f,0.f}; ps[mi] = z; }
                int r = si * 16 + lr;
                #pragma unroll
                for (int kk = 0; kk < 4; ++kk) {
                    int co = kk * 32 + lg * 8;
                    half8 bb = *(const half8*)(bsc + r * 128 + (co ^ ((r & 7) << 3)));
                    #pragma unroll
                    for (int mi = 0; mi < 4; ++mi)
                        ps[mi] = __builtin_amdgcn_mfma_f32_16x16x32_f16(bb, ca[mi][kk], ps[mi], 0, 0, 0);
                }
                // coef + vectorized P write (lane holds l = mi*16+lr, s = st*64+si*16+lg*4+r)
                if (st < w) {
                    float fs[4];
                    #pragma unroll
                    for (int rr = 0; rr < 4; ++rr) {
                        int sg = st * 64 + si * 16 + lg * 4 + rr;
                        fs[rr] = expf(c0 - cumL[sg]) * dtL[sg];
                    }
                    #pragma unroll
                    for (int mi = 0; mi < 4; ++mi) {
                        half4 hv;
                        #pragma unroll
                        for (int rr = 0; rr < 4; ++rr)
                            hv[rr] = (_Float16)(ps[mi][rr] * el[mi] * fs[rr]);
                        *(half4*)(pwb + (mi * 16 + lr) * 64 + ((si * 16 + lg * 4) ^ (8 * (lr & 7)))) = hv;
                    }
                } else { // diagonal tile: masked direct exp, + D on the diagonal
                    #pragma unroll
                    for (int mi = 0; mi < 4; ++mi) {
                        int lloc = mi * 16 + lr;
                        float cl = cumL[w * 64 + lloc];
                        half4 hv;
                        #pragma unroll
                        for (int rr = 0; rr < 4; ++rr) {
                            int sl = si * 16 + lg * 4 + rr;
                            float v = 0.f;
                            if (sl <= lloc) {
                                int sg = w * 64 + sl;
                                v = ps[mi][rr] * expf(cl - cumL[sg]) * dtL[sg];
                                if (sl == lloc) v += Dv;
                            }
                            hv[rr] = (_Float16)v;
                        }
                        *(half4*)(pwb + (mi * 16 + lr) * 64 + ((si * 16 + lg * 4) ^ (8 * (lr & 7)))) = hv;
                    }
                }
            }
            // PV: D[l][p] += sum_s P[l,s] * xT[p,s]
            #pragma unroll
            for (int k2 = 0; k2 < 2; ++k2) {
                int co = k2 * 32 + lg * 8;
                half8 pa[4];
                #pragma unroll
                for (int mi = 0; mi < 4; ++mi) {
                    int r = mi * 16 + lr;
                    pa[mi] = *(const half8*)(pwb + r * 64 + (co ^ (8 * (lr & 7))));
                }
                #pragma unroll
                for (int pi = 0; pi < 4; ++pi)
                    #pragma unroll
                    for (int mi = 0; mi < 4; ++mi)
                        yacc[mi][pi] = __builtin_amdgcn_mfma_f32_16x16x32_f16(pa[mi], xb[pi][k2], yacc[mi][pi], 0, 0, 0);
            }
        }
        __syncthreads();   // end-iter: staging(st+1) resident, buffers safe
    }

    // epilogue (D*x already folded into P diagonal)
    #pragma unroll
    for (int mi = 0; mi < 4; ++mi) {
        #pragma unroll
        for (int r = 0; r < 4; ++r) {
            int l = w * 64 + mi * 16 + lg * 4 + r;
            size_t row = (size_t)bc * 256 + l;
            #pragma unroll
            for (int pi = 0; pi < 4; ++pi)
                y[row * DSSM + h * 64 + pi * 16 + lr] = yacc[mi][pi][r];
        }
    }
}

// ---------------------------------------------------------------------------
// Gated RMSNorm -> f16 output for out_proj MFMA
// ---------------------------------------------------------------------------
__global__ __launch_bounds__(256) void norm_kernel(const float* __restrict__ y,
                                                   const float* __restrict__ zx,
                                                   const float* __restrict__ norm_w,
                                                   _Float16* __restrict__ outh) {
    int m = blockIdx.x;
    int t = threadIdx.x;
    const float* yrow = y + (size_t)m * DSSM;
    const float* zrow = zx + (size_t)m * DINPROJ;
    float yg[8];
    float ss = 0.f;
    #pragma unroll
    for (int q = 0; q < 2; ++q) {
        float4 yv = *(const float4*)(yrow + t*8 + q*4);
        float4 zv = *(const float4*)(zrow + t*8 + q*4);
        float zvals[4] = {zv.x, zv.y, zv.z, zv.w};
        float yvals[4] = {yv.x, yv.y, yv.z, yv.w};
        #pragma unroll
        for (int i = 0; i < 4; ++i) {
            float sz = zvals[i] / (1.f + expf(-zvals[i]));
            float g = yvals[i] * sz;
            yg[q*4+i] = g;
            ss += g * g;
        }
    }
    #pragma unroll
    for (int off = 32; off > 0; off >>= 1) ss += __shfl_xor(ss, off, 64);
    __shared__ float red[4];
    if ((t & 63) == 0) red[t >> 6] = ss;
    __syncthreads();
    float tot = red[0] + red[1] + red[2] + red[3];
    float inv = rsqrtf(tot / (float)DSSM + EPSF);
    half8 h;
    #pragma unroll
    for (int q = 0; q < 8; ++q)
        h[q] = (_Float16)(yg[q] * inv * norm_w[t*8 + q]);
    *(half8*)(outh + (size_t)m * DSSM + t * 8) = h;
}

// ---------------------------------------------------------------------------
extern "C" void kernel_launch(void* const* d_in, const int* in_sizes, int n_in,
                              void* d_out, int out_size, void* d_ws, size_t ws_size,
                              hipStream_t stream) {
    (void)in_sizes; (void)n_in; (void)out_size; (void)ws_size;
    const float* u       = (const float*)d_in[0];
    const float* W_in    = (const float*)d_in[1];
    const float* conv_w  = (const float*)d_in[2];
    const float* conv_b  = (const float*)d_in[3];
    const float* dt_bias = (const float*)d_in[4];
    const float* A_log   = (const float*)d_in[5];
    const float* Dp      = (const float*)d_in[6];
    const float* norm_w  = (const float*)d_in[7];
    const float* W_out   = (const float*)d_in[8];
    float* out = (float*)d_out;

    // workspace layout
    float* zx   = (float*)d_ws;                       // ROWS*DINPROJ
    float* dtb  = zx   + (size_t)ROWS * DINPROJ;      // ROWS*NHEADS
    float* cum  = dtb  + (size_t)ROWS * NHEADS;
    float* Sbuf = cum  + (size_t)ROWS * NHEADS;       // 512*64*128
    float* yb   = Sbuf + (size_t)NBC * NHEADS * DHEAD * DSTATE;  // ROWS*DSSM
    _Float16* xbc_h = (_Float16*)(yb + (size_t)ROWS * DSSM);     // ROWS*CONVDIM
    _Float16* xTg   = xbc_h + (size_t)ROWS * CONVDIM;            // 512*64*256
    _Float16* BTg   = xTg   + (size_t)NBC * NHEADS * 64 * 256;   // 16*128*256
    _Float16* uh    = BTg   + (size_t)NBC * 128 * 256;
    _Float16* Wih   = uh    + (size_t)ROWS * DMODEL;
    _Float16* Wouth = Wih   + (size_t)NPAD * DMODEL;
    _Float16* ybh   = Wouth + (size_t)DMODEL * DSSM;

    // casts
    cast_f16_kernel<<<(ROWS * DMODEL / 8 + 255) / 256, 256, 0, stream>>>(u, uh, ROWS * DMODEL / 8);
    cast_pad_f16_kernel<<<(NPAD * DMODEL / 8 + 255) / 256, 256, 0, stream>>>(
        W_in, Wih, DINPROJ, DMODEL, NPAD * DMODEL / 8);
    cast_f16_kernel<<<(DMODEL * DSSM / 8 + 255) / 256, 256, 0, stream>>>(W_out, Wouth, DMODEL * DSSM / 8);

    // 1. in_proj
    gemm_f16<4, 4><<<dim3(NPAD / 128, ROWS / 128), 256, 0, stream>>>(
        uh, Wih, zx, DMODEL, DINPROJ, DINPROJ);
    // 2. conv + silu -> f16 xbc + transposed copies (tiled, coalesced)
    conv_silu_kernel<<<NBC * 36, 256, 0, stream>>>(
        zx, conv_w, conv_b, xbc_h, xTg, BTg);
    // 3. dt
    dt_kernel<<<(ROWS * NHEADS + 255) / 256, 256, 0, stream>>>(zx, dt_bias, dtb);
    // 4. cumsum
    cumsum_kernel<<<2, 256, 0, stream>>>(dtb, A_log, cum);
    // 5. chunk states (MFMA)
    chunk_state_mfma<<<NBC * NHEADS, 256, 0, stream>>>(xTg, BTg, dtb, cum, Sbuf);
    // 6. inter-chunk scan
    scan_kernel<<<BATCH * NHEADS, 256, 0, stream>>>(cum, Sbuf);
    // 7. Y (MFMA v2)
    y_mfma<<<NBC * NHEADS, 256, 0, stream>>>(xbc_h, xTg, dtb, cum, Sbuf, Dp, yb);
    // 8. gated RMSNorm -> f16
    norm_kernel<<<ROWS, 256, 0, stream>>>(yb, zx, norm_w, ybh);
    // 9. out_proj
    gemm_f16<4, 2><<<dim3(DMODEL / 64, ROWS / 128), 256, 0, stream>>>(
        ybh, Wouth, out, DSSM, DMODEL, DMODEL);
}